// Round 15
// baseline (407.427 us; speedup 1.0000x reference)
//
#include <hip/hip_runtime.h>
#include <math.h>

#define HW_ 65536

typedef __attribute__((ext_vector_type(8))) short b16x8;
typedef __attribute__((ext_vector_type(4))) short b16x4;
typedef __attribute__((ext_vector_type(4))) float f32x4;

__device__ __forceinline__ unsigned short f2b(float f) {
    union { float f; unsigned u; } v; v.f = f;
    unsigned r = v.u + 0x7fffu + ((v.u >> 16) & 1u);
    return (unsigned short)(r >> 16);
}
__device__ __forceinline__ float b2f(unsigned short h) {
    union { unsigned u; float f; } v; v.u = ((unsigned)h) << 16; return v.f;
}
__device__ __forceinline__ float gelu_f(float x) {
    float t = 0.7978845608f * fmaf(0.044715f * x, x * x, x);
    float e = __expf(2.f * t);
    float th = 1.f - 2.f / (e + 1.f);
    return 0.5f * x * (1.f + th);
}

__device__ __forceinline__ float wave_reduce_sum(float v) {
    #pragma unroll
    for (int off = 32; off; off >>= 1) v += __shfl_down(v, off, 64);
    return v;
}

// Blocked bf16 layout: element (px, ch) of a CC*8-channel tensor lives at
//   ((px>>4)*CC + (ch>>3))*128 + (px&15)*8 + (ch&7)
__device__ __forceinline__ size_t baddr(long px, int CC, int g) {
    return (((size_t)(px >> 4)) * CC + g) * 128 + ((size_t)(px & 15) << 3);
}

// ---------------------------------------------------------------------------
// Weight prep (unchanged).
// ---------------------------------------------------------------------------
__global__ __launch_bounds__(256) void wprep_k(
    const float* __restrict__ q1w, const float* __restrict__ q2w,
    const float* __restrict__ m1w, const float* __restrict__ m2w,
    const float* __restrict__ pEw, const float* __restrict__ p1w,
    const float* __restrict__ p2w, const float* __restrict__ o1w,
    const float* __restrict__ o2w,
    const float* __restrict__ q1dw, const float* __restrict__ q2dw,
    const float* __restrict__ pEdw, const float* __restrict__ p1dw,
    const float* __restrict__ p2dw,
    unsigned short* __restrict__ wt, float* __restrict__ dwt)
{
    const int idx = blockIdx.x * 256 + threadIdx.x;
    if (idx < 135168) {
        const int base[8] = {0,9216,18432,21504,24576,61440,98304,116736};
        int s = 0;
        #pragma unroll
        for (int i = 1; i < 8; i++) if (idx >= base[i]) s = i;
        const int local = idx - base[s];
        float v = 0.f;
        if (s < 4) {
            const int m = local >> 6, k = local & 63;
            const float* src = (s == 0) ? q1w : (s == 1) ? q2w : (s == 2) ? m1w : m2w;
            if (k < 48) v = src[m * 48 + k];
        } else if (s < 6) {
            const int br = s - 4;
            const int m = local / 96, k = local % 96;
            if (m < 192) {
                v = pEw[(size_t)(br * 192 + m) * 96 + k];
            } else {
                const float* p12 = br ? p2w : p1w;
                const int lo = br * 48, m2 = m - 192;
                if (k >= lo && k < lo + 48) v = p12[m2 * 48 + (k - lo)];
            }
        } else {
            const int m = local / 192, k = local % 192;
            v = ((s == 6) ? o1w : o2w)[m * 192 + k];
        }
        wt[idx] = f2b(v);
    } else if (idx < 135168 + 9504) {
        const int d = idx - 135168;
        const int dbase[5] = {0,1296,2592,6048,7776};
        const int Cs[5] = {144,144,384,192,192};
        int s = 0;
        #pragma unroll
        for (int i = 1; i < 5; i++) if (d >= dbase[i]) s = i;
        const int local = d - dbase[s], C = Cs[s];
        const int t = local / C, c = local % C;
        const float* src = (s == 0) ? q1dw : (s == 1) ? q2dw : (s == 2) ? pEdw
                         : (s == 3) ? p1dw : p2dw;
        dwt[d] = src[c * 9 + t];
    }
}

// ---------------------------------------------------------------------------
// MFMA GEMM (unchanged; used for qkv and GH).
// ---------------------------------------------------------------------------
template<int BM, int KC, int NT, int BSRC, int EPI, bool GRIDSWAP>
__global__ __launch_bounds__(256) void gemm_k(
    const unsigned short* __restrict__ B16,
    const float* __restrict__ Bf32, int Cin,
    const unsigned short* __restrict__ W16,
    unsigned short* __restrict__ out16, int CCo, int Coff,
    float* __restrict__ outf, const unsigned short* __restrict__ res,
    const unsigned short* __restrict__ acc16)
{
    constexpr int MF = BM / 16;
    const int tid = threadIdx.x;
    const int lane = tid & 63, w = tid >> 6;
    const int lm = lane & 15, lk = lane >> 4;
    const int mb = GRIDSWAP ? blockIdx.x : blockIdx.y;
    const int pxblk = GRIDSWAP ? blockIdx.y : blockIdx.x;
    const int m0 = mb * BM;
    const long wavepx = ((long)pxblk * 4 + w) * (NT * 16);
    const long pxb0 = wavepx >> 4;

    f32x4 acc[NT][MF];
    #pragma unroll
    for (int nt = 0; nt < NT; nt++)
        #pragma unroll
        for (int m = 0; m < MF; m++)
            #pragma unroll
            for (int j = 0; j < 4; j++) acc[nt][m][j] = 0.f;

    #pragma unroll
    for (int kc = 0; kc < KC; kc++) {
        b16x8 a[MF];
        #pragma unroll
        for (int m = 0; m < MF; m++)
            a[m] = *(const b16x8*)&W16[(size_t)(m0 + m * 16 + lm) * (KC * 32) + kc * 32 + lk * 8];
        #pragma unroll
        for (int nt = 0; nt < NT; nt++) {
            b16x8 bb;
            if (BSRC == 0) {
                bb = *(const b16x8*)&B16[((pxb0 + nt) * (KC * 4) + (kc * 4 + lk)) * 128 + lm * 8];
            } else {
                const long px = wavepx + nt * 16 + lm;
                const int p = (int)(px & 65535), bat = (int)(px >> 16);
                #pragma unroll
                for (int j = 0; j < 8; j++) {
                    const int c = kc * 32 + lk * 8 + j;
                    float v = (c < Cin) ? Bf32[((size_t)(bat * Cin + c) << 16) + p] : 0.f;
                    bb[j] = (short)f2b(v);
                }
            }
            #pragma unroll
            for (int m = 0; m < MF; m++)
                acc[nt][m] = __builtin_amdgcn_mfma_f32_16x16x32_bf16(a[m], bb, acc[nt][m], 0, 0, 0);
        }
    }

    #pragma unroll
    for (int nt = 0; nt < NT; nt++) {
        const long px = wavepx + nt * 16 + lm;
        #pragma unroll
        for (int m = 0; m < MF; m++) {
            const int mrow = m * 16 + lk * 4;
            if (EPI == 0) {
                b16x4 o;
                #pragma unroll
                for (int j = 0; j < 4; j++) o[j] = (short)f2b(acc[nt][m][j]);
                const int ch = Coff + m0 + mrow;
                *(b16x4*)&out16[((pxb0 + nt) * CCo + (ch >> 3)) * 128 + lm * 8 + (ch & 7)] = o;
            } else if (EPI == 1) {
                const int p = (int)(px & 65535), bat = (int)(px >> 16);
                b16x4 r4 = *(const b16x4*)&res[((pxb0 + nt) * 12 + (mrow >> 3)) * 128 + lm * 8 + (mrow & 7)];
                #pragma unroll
                for (int j = 0; j < 4; j++)
                    outf[((size_t)(bat * 96 + mrow + j) << 16) + p]
                        = acc[nt][m][j] + b2f((unsigned short)r4[j]);
            } else if (EPI == 2) {
                const int p = (int)(px & 65535), bat = (int)(px >> 16);
                #pragma unroll
                for (int j = 0; j < 4; j++) {
                    const size_t adr = ((size_t)(bat * 96 + mrow + j) << 16) + p;
                    outf[adr] += acc[nt][m][j];
                }
            } else {
                const int p = (int)(px & 65535), bat = (int)(px >> 16);
                const size_t boffi = ((pxb0 + nt) * 12 + (mrow >> 3)) * 128 + lm * 8 + (mrow & 7);
                b16x4 r4 = *(const b16x4*)&res[boffi];
                b16x4 a4 = *(const b16x4*)&acc16[boffi];
                #pragma unroll
                for (int j = 0; j < 4; j++)
                    outf[((size_t)(bat * 96 + mrow + j) << 16) + p]
                        = acc[nt][m][j] + b2f((unsigned short)r4[j]) + b2f((unsigned short)a4[j]);
            }
        }
    }
}

// ---------------------------------------------------------------------------
// dw 4px row core with static addressing (proven).
// ---------------------------------------------------------------------------
__device__ __forceinline__ void unpack8(const uint4 u, float f[8]) {
    union { unsigned u; float f; } a;
    a.u = u.x << 16;         f[0] = a.f;
    a.u = u.x & 0xFFFF0000u; f[1] = a.f;
    a.u = u.y << 16;         f[2] = a.f;
    a.u = u.y & 0xFFFF0000u; f[3] = a.f;
    a.u = u.z << 16;         f[4] = a.f;
    a.u = u.z & 0xFFFF0000u; f[5] = a.f;
    a.u = u.w << 16;         f[6] = a.f;
    a.u = u.w & 0xFFFF0000u; f[7] = a.f;
}

__device__ __forceinline__ void dw_row4(
    float acc[4][8], const unsigned short* __restrict__ T,
    size_t cb, long lOff, long rOff, bool lval, bool rval,
    const float* __restrict__ wrow, int wstr)
{
    float w[3][8];
    #pragma unroll
    for (int tx = 0; tx < 3; tx++) {
        const float4 a = *(const float4*)(wrow + (size_t)tx * wstr);
        const float4 b = *(const float4*)(wrow + (size_t)tx * wstr + 4);
        w[tx][0] = a.x; w[tx][1] = a.y; w[tx][2] = a.z; w[tx][3] = a.w;
        w[tx][4] = b.x; w[tx][5] = b.y; w[tx][6] = b.z; w[tx][7] = b.w;
    }
    uint4 u[6];
    if (lval) u[0] = *(const uint4*)&T[cb + lOff];
    else      u[0] = make_uint4(0u, 0u, 0u, 0u);
    #pragma unroll
    for (int c = 0; c < 4; c++) u[c + 1] = *(const uint4*)&T[cb + (size_t)c * 8];
    if (rval) u[5] = *(const uint4*)&T[cb + rOff];
    else      u[5] = make_uint4(0u, 0u, 0u, 0u);

    #pragma unroll
    for (int d = 0; d < 6; d++) {
        float f[8];
        unpack8(u[d], f);
        #pragma unroll
        for (int tx = 0; tx < 3; tx++) {
            const int p = d - tx;
            if (p >= 0 && p < 4)
                #pragma unroll
                for (int j = 0; j < 8; j++)
                    acc[p][j] = fmaf(w[tx][j], f[j], acc[p][j]);
        }
    }
}

// phase-1 depthwise: 144 ch (18 chunks), both branches via blockIdx.z.
__global__ __launch_bounds__(256) void dw144_k(
    const unsigned short* __restrict__ in1, unsigned short* __restrict__ out1,
    const unsigned short* __restrict__ in2, unsigned short* __restrict__ out2,
    const float* __restrict__ dwt)
{
    const int z = blockIdx.z;
    const unsigned short* in = z ? in2 : in1;
    unsigned short* out = z ? out2 : out1;
    const float* wt = dwt + z * 1296;
    const int bx = blockIdx.x;
    const int sb = (bx & 7) * 288 + (bx >> 3);
    const int idx = sb * 256 + threadIdx.x;   // < 589824
    const int pbi = idx / 72;
    const int rem = idx - pbi * 72;
    const int g = rem >> 2, i = rem & 3;
    const long px0 = (long)pbi * 16 + i * 4;
    const int x0 = (int)(px0 & 255);
    const int y = (int)((px0 >> 8) & 255);
    const bool lval = x0 > 0, rval = x0 < 252;
    const int off = (int)(px0 & 15) * 8;
    const size_t cb0 = ((size_t)(px0 >> 4) * 18 + g) * 128 + off;
    const long lOff = (off == 0) ? (120 - 18 * 128) : -8;
    const long rOff = (off == 96) ? (18 * 128 - 96) : 32;
    const long dyStep = 16 * 18 * 128;

    float acc[4][8];
    #pragma unroll
    for (int p = 0; p < 4; p++)
        #pragma unroll
        for (int j = 0; j < 8; j++) acc[p][j] = 0.f;

    #pragma unroll
    for (int dy = -1; dy <= 1; dy++) {
        const int yy = y + dy;
        if ((unsigned)yy >= 256u) continue;
        const size_t cb = cb0 + (size_t)((long)dy * dyStep);
        dw_row4(acc, in, cb, lOff, rOff, lval, rval,
                wt + g * 8 + (size_t)(dy + 1) * 3 * 144, 144);
    }

    #pragma unroll
    for (int p = 0; p < 4; p++) {
        b16x8 o;
        #pragma unroll
        for (int j = 0; j < 8; j++) o[j] = (short)f2b(acc[p][j]);
        *(b16x8*)&out[cb0 + (size_t)p * 8] = o;
    }
}

// ---------------------------------------------------------------------------
// FUSED tail: dw(G)+gelu * dw(H) for a 64px x 192ch tile -> LDS, then
// po GEMM (96x192) against the LDS tile. 384 threads = 16 px-groups x 24
// chunks (dw phase) = 6 waves (GEMM phase). Grid 2048, XCD y-banded.
// EPI 0: store bf16 blocked ACC. EPI 3: dout = b2f(res)+b2f(acc16)+acc.
// ---------------------------------------------------------------------------
template<int EPI>
__global__ __launch_bounds__(384) void dwpo_k(
    const unsigned short* __restrict__ GH,
    const float* __restrict__ dwtG, const float* __restrict__ dwtH,
    const unsigned short* __restrict__ Wpo,
    unsigned short* __restrict__ ACC, float* __restrict__ dout,
    const unsigned short* __restrict__ res,
    const unsigned short* __restrict__ acc16)
{
    __shared__ unsigned short XgS[4 * 24 * 136];   // padded rows: 26112 B
    const int bx = blockIdx.x;
    const int tile = (bx & 7) * 256 + (bx >> 3);   // 2048 tiles of 64 px
    const int tid = threadIdx.x;

    // ---- phase 1: depthwise + gelu-gate into LDS
    {
        const int pg = tid / 24;          // 0..15
        const int g  = tid - pg * 24;     // 0..23
        const long px0 = (long)tile * 64 + pg * 4;
        const int x0 = (int)(px0 & 255);
        const int y = (int)((px0 >> 8) & 255);
        const bool lval = x0 > 0, rval = x0 < 252;
        const int off = (int)(px0 & 15) * 8;
        const size_t cb0 = ((size_t)(px0 >> 4) * 48 + g) * 128 + off;
        const long lOff = (off == 0) ? (120 - 48 * 128) : -8;
        const long rOff = (off == 96) ? (48 * 128 - 96) : 32;
        const long dyStep = 16 * 48 * 128;

        float aG[4][8], aH[4][8];
        #pragma unroll
        for (int p = 0; p < 4; p++)
            #pragma unroll
            for (int j = 0; j < 8; j++) { aG[p][j] = 0.f; aH[p][j] = 0.f; }

        #pragma unroll
        for (int dy = -1; dy <= 1; dy++) {
            const int yy = y + dy;
            if ((unsigned)yy >= 256u) continue;
            const size_t cb = cb0 + (size_t)((long)dy * dyStep);
            dw_row4(aG, GH, cb, lOff, rOff, lval, rval,
                    dwtG + g * 8 + (size_t)(dy + 1) * 3 * 384, 384);
            dw_row4(aH, GH, cb + 3072, lOff, rOff, lval, rval,
                    dwtH + g * 8 + (size_t)(dy + 1) * 3 * 192, 192);
        }

        const int pxl0 = pg * 4;
        #pragma unroll
        for (int p = 0; p < 4; p++) {
            const int pxl = pxl0 + p;
            b16x8 o;
            #pragma unroll
            for (int j = 0; j < 8; j++)
                o[j] = (short)f2b(gelu_f(aG[p][j]) * aH[p][j]);
            *(b16x8*)&XgS[((pxl >> 4) * 24 + g) * 136 + (pxl & 15) * 8] = o;
        }
    }
    __syncthreads();

    // ---- phase 2: po GEMM 96 x 64 from LDS tile
    {
        const int lane = tid & 63, w = tid >> 6;   // 6 waves
        const int lm = lane & 15, lk = lane >> 4;
        const int m0 = w * 16;
        f32x4 acc[4];
        #pragma unroll
        for (int nt = 0; nt < 4; nt++)
            #pragma unroll
            for (int j = 0; j < 4; j++) acc[nt][j] = 0.f;

        #pragma unroll
        for (int kc = 0; kc < 6; kc++) {
            b16x8 a = *(const b16x8*)&Wpo[(size_t)(m0 + lm) * 192 + kc * 32 + lk * 8];
            #pragma unroll
            for (int nt = 0; nt < 4; nt++) {
                b16x8 bb = *(const b16x8*)&XgS[(nt * 24 + kc * 4 + lk) * 136 + lm * 8];
                acc[nt] = __builtin_amdgcn_mfma_f32_16x16x32_bf16(a, bb, acc[nt], 0, 0, 0);
            }
        }

        const long pxb0 = (long)tile * 4;
        const int ch = m0 + lk * 4;
        #pragma unroll
        for (int nt = 0; nt < 4; nt++) {
            const long pxb = pxb0 + nt;
            if (EPI == 0) {
                b16x4 o;
                #pragma unroll
                for (int j = 0; j < 4; j++) o[j] = (short)f2b(acc[nt][j]);
                *(b16x4*)&ACC[(pxb * 12 + (ch >> 3)) * 128 + lm * 8 + (ch & 7)] = o;
            } else {
                const long px = pxb * 16 + lm;
                const int p = (int)(px & 65535), bat = (int)(px >> 16);
                const size_t boffi = (pxb * 12 + (ch >> 3)) * 128 + lm * 8 + (ch & 7);
                b16x4 r4 = *(const b16x4*)&res[boffi];
                b16x4 a4 = *(const b16x4*)&acc16[boffi];
                #pragma unroll
                for (int j = 0; j < 4; j++)
                    dout[((size_t)(bat * 96 + ch + j) << 16) + p]
                        = acc[nt][j] + b2f((unsigned short)r4[j]) + b2f((unsigned short)a4[j]);
            }
        }
    }
}

// ---------------------------------------------------------------------------
// Attention stage A (unchanged).
// ---------------------------------------------------------------------------
__global__ __launch_bounds__(256) void attnA_k(
    const unsigned short* __restrict__ Q1, const unsigned short* __restrict__ Q2,
    float* __restrict__ part)
{
    const int tid = threadIdx.x;
    const int chunk = blockIdx.x, bh = blockIdx.y, a = blockIdx.z;
    const int b = bh >> 3, h = bh & 7;
    const unsigned* Qq = (const unsigned*)(a ? Q1 : Q2);
    const unsigned* Qk = (const unsigned*)(a ? Q2 : Q1);
    const int u0 = h * 3;
    const int cq = u0 >> 2, o = u0 & 3;
    const int ck = (24 + u0) >> 2;

    float dot[36], nq[6], nk[6];
    #pragma unroll
    for (int i = 0; i < 36; i++) dot[i] = 0.f;
    #pragma unroll
    for (int i = 0; i < 6; i++) { nq[i] = 0.f; nk[i] = 0.f; }

    #pragma unroll 1
    for (int r = 0; r < 8; r++) {
        const long px = (long)b * 65536 + chunk * 2048 + r * 256 + tid;
        const size_t rowu = ((size_t)(px >> 4)) * 18 * 64 + ((px & 15) << 2);
        const uint4 qa = *(const uint4*)&Qq[rowu + (size_t)cq * 64];
        const uint4 qb = *(const uint4*)&Qq[rowu + (size_t)(cq + 1) * 64];
        const uint4 ka = *(const uint4*)&Qk[rowu + (size_t)ck * 64];
        const uint4 kb = *(const uint4*)&Qk[rowu + (size_t)(ck + 1) * 64];
        unsigned uq[3], uk[3];
        if (o == 0)      { uq[0]=qa.x; uq[1]=qa.y; uq[2]=qa.z; uk[0]=ka.x; uk[1]=ka.y; uk[2]=ka.z; }
        else if (o == 1) { uq[0]=qa.y; uq[1]=qa.z; uq[2]=qa.w; uk[0]=ka.y; uk[1]=ka.z; uk[2]=ka.w; }
        else if (o == 2) { uq[0]=qa.z; uq[1]=qa.w; uq[2]=qb.x; uk[0]=ka.z; uk[1]=ka.w; uk[2]=kb.x; }
        else             { uq[0]=qa.w; uq[1]=qb.x; uq[2]=qb.y; uk[0]=ka.w; uk[1]=kb.x; uk[2]=kb.y; }
        float q[6], k[6];
        #pragma unroll
        for (int i = 0; i < 3; i++) {
            union { unsigned u; float f; } lo, hi;
            lo.u = uq[i] << 16; hi.u = uq[i] & 0xFFFF0000u;
            q[2 * i] = lo.f; q[2 * i + 1] = hi.f;
            lo.u = uk[i] << 16; hi.u = uk[i] & 0xFFFF0000u;
            k[2 * i] = lo.f; k[2 * i + 1] = hi.f;
        }
        #pragma unroll
        for (int c = 0; c < 6; c++) nq[c] = fmaf(q[c], q[c], nq[c]);
        #pragma unroll
        for (int d = 0; d < 6; d++) nk[d] = fmaf(k[d], k[d], nk[d]);
        #pragma unroll
        for (int c = 0; c < 6; c++)
            #pragma unroll
            for (int d = 0; d < 6; d++) dot[c * 6 + d] = fmaf(q[c], k[d], dot[c * 6 + d]);
    }

    __shared__ float red[4][48];
    const int lane = tid & 63, wid = tid >> 6;
    #pragma unroll
    for (int i = 0; i < 48; i++) {
        float v = (i < 36) ? dot[i] : (i < 42 ? nq[i - 36] : nk[i - 42]);
        v = wave_reduce_sum(v);
        if (!lane) red[wid][i] = v;
    }
    __syncthreads();
    if (tid < 48)
        part[((size_t)((a * 16 + bh) * 32 + chunk)) * 48 + tid]
            = red[0][tid] + red[1][tid] + red[2][tid] + red[3][tid];
}

__global__ void attnB_k(const float* __restrict__ part,
                        const float* __restrict__ t1, const float* __restrict__ t2,
                        float* __restrict__ att)
{
    const int abh = blockIdx.x, tid = threadIdx.x;
    const int a = abh >> 4, b = (abh >> 3) & 1, h = abh & 7;
    __shared__ float s[48];
    if (tid < 48) {
        float v = 0.f;
        for (int ch = 0; ch < 32; ch++) v += part[((size_t)abh * 32 + ch) * 48 + tid];
        s[tid] = v;
    }
    __syncthreads();
    if (tid < 6) {
        const int c = tid;
        const float tv = a ? t2[h] : t1[h];
        const float qn = fmaxf(sqrtf(s[36 + c]), 1e-12f);
        float raw[6];
        #pragma unroll
        for (int d = 0; d < 6; d++)
            raw[d] = tv * s[c * 6 + d] / (qn * fmaxf(sqrtf(s[42 + d]), 1e-12f));
        float m = raw[0];
        #pragma unroll
        for (int d = 1; d < 6; d++) m = fmaxf(m, raw[d]);
        float e[6], sum = 0.f;
        #pragma unroll
        for (int d = 0; d < 6; d++) { e[d] = expf(raw[d] - m); sum += e[d]; }
        const float inv = 1.f / sum;
        #pragma unroll
        for (int d = 0; d < 6; d++)
            att[((size_t)(a * 2 + b) * 8 + h) * 36 + c * 6 + d] = e[d] * inv;
    }
}

// ---------------------------------------------------------------------------
// Fused attn-out + mid conv + residual (unchanged).
// ---------------------------------------------------------------------------
__global__ __launch_bounds__(256) void mid_k(
    const unsigned short* __restrict__ Q1, const unsigned short* __restrict__ Q2,
    const float* __restrict__ att,
    const float* __restrict__ x1, const float* __restrict__ x2,
    const unsigned short* __restrict__ Wm, unsigned short* __restrict__ D16p)
{
    const int br = blockIdx.y;
    const unsigned short* Qv = br ? Q2 : Q1;
    const float* x = br ? x2 : x1;
    const unsigned short* W16 = Wm + br * 3072;
    const float* attb = att + br * 576;
    const int boff = br * 48;

    __shared__ float atts[288];
    __shared__ unsigned short S[256][72];
    const int tid = threadIdx.x;
    const long px = (long)blockIdx.x * 256 + tid;
    const int bat = (int)(px >> 16);

    for (int i = tid; i < 288; i += 256) atts[i] = attb[bat * 288 + i];

    float v[48];
    #pragma unroll
    for (int i = 0; i < 6; i++) {
        b16x8 t = *(const b16x8*)&Qv[baddr(px, 18, 12 + i)];
        #pragma unroll
        for (int j = 0; j < 8; j++) v[i * 8 + j] = b2f((unsigned short)t[j]);
    }
    __syncthreads();

    #pragma unroll
    for (int h = 0; h < 8; h++) {
        unsigned short sh[6];
        #pragma unroll
        for (int c = 0; c < 6; c++) {
            float s = 0.f;
            #pragma unroll
            for (int d = 0; d < 6; d++) s = fmaf(atts[h * 36 + c * 6 + d], v[h * 6 + d], s);
            sh[c] = f2b(s);
        }
        #pragma unroll
        for (int i = 0; i < 3; i++) {
            unsigned packed = (unsigned)sh[2 * i] | ((unsigned)sh[2 * i + 1] << 16);
            *(unsigned*)&S[tid][h * 6 + 2 * i] = packed;
        }
    }
    #pragma unroll
    for (int i = 0; i < 8; i++) *(unsigned*)&S[tid][48 + 2 * i] = 0u;
    __syncthreads();

    const int lane = tid & 63, w = tid >> 6;
    const int lm = lane & 15, lk = lane >> 4;
    f32x4 acc[4][3];
    #pragma unroll
    for (int nt = 0; nt < 4; nt++)
        #pragma unroll
        for (int m = 0; m < 3; m++)
            #pragma unroll
            for (int j = 0; j < 4; j++) acc[nt][m][j] = 0.f;

    #pragma unroll
    for (int kc = 0; kc < 2; kc++) {
        b16x8 a[3];
        #pragma unroll
        for (int m = 0; m < 3; m++)
            a[m] = *(const b16x8*)&W16[(size_t)(m * 16 + lm) * 64 + kc * 32 + lk * 8];
        #pragma unroll
        for (int nt = 0; nt < 4; nt++) {
            b16x8 bb = *(const b16x8*)&S[w * 64 + nt * 16 + lm][kc * 32 + lk * 8];
            #pragma unroll
            for (int m = 0; m < 3; m++)
                acc[nt][m] = __builtin_amdgcn_mfma_f32_16x16x32_bf16(a[m], bb, acc[nt][m], 0, 0, 0);
        }
    }

    #pragma unroll
    for (int nt = 0; nt < 4; nt++) {
        const long px2 = (long)blockIdx.x * 256 + w * 64 + nt * 16 + lm;
        const int p2 = (int)(px2 & 65535);
        const long pxb2 = px2 >> 4;
        #pragma unroll
        for (int m = 0; m < 3; m++) {
            const int row = m * 16 + lk * 4;
            b16x4 o;
            #pragma unroll
            for (int j = 0; j < 4; j++) {
                float xv = x[((size_t)(bat * 48 + row + j) << 16) + p2];
                o[j] = (short)f2b(acc[nt][m][j] + xv);
            }
            const int ch = boff + row;
            *(b16x4*)&D16p[(pxb2 * 12 + (ch >> 3)) * 128 + lm * 8 + (ch & 7)] = o;
        }
    }
}

extern "C" void kernel_launch(void* const* d_in, const int* in_sizes, int n_in,
                              void* d_out, int out_size, void* d_ws, size_t ws_size,
                              hipStream_t stream) {
    const float* x1      = (const float*)d_in[0];
    const float* x2      = (const float*)d_in[1];
    const float* t1      = (const float*)d_in[2];
    const float* t2      = (const float*)d_in[3];
    const float* qkv1_w  = (const float*)d_in[4];
    const float* qkv1_dw = (const float*)d_in[5];
    const float* qkv2_w  = (const float*)d_in[6];
    const float* qkv2_dw = (const float*)d_in[7];
    const float* mid1_w  = (const float*)d_in[8];
    const float* mid2_w  = (const float*)d_in[9];
    const float* pE_w    = (const float*)d_in[10];
    const float* pE_dw   = (const float*)d_in[11];
    const float* pE1_w   = (const float*)d_in[12];
    const float* pE1_dw  = (const float*)d_in[13];
    const float* pE2_w   = (const float*)d_in[14];
    const float* pE2_dw  = (const float*)d_in[15];
    const float* po1_w   = (const float*)d_in[16];
    const float* po2_w   = (const float*)d_in[17];
    float* dout = (float*)d_out;
    char* ws = (char*)d_ws;

    // workspace layout (bytes); peak ~201.8 MB
    unsigned short* D16p  = (unsigned short*)(ws + 0);
    unsigned short* QKVc1 = (unsigned short*)(ws + 25165824);
    unsigned short* QKVc2 = (unsigned short*)(ws + 62914560);
    unsigned short* Q1    = (unsigned short*)(ws + 100663296);
    unsigned short* Q2    = (unsigned short*)(ws + 138412032);
    unsigned short* GH    = (unsigned short*)(ws + 25165824);     // phase5 overlay
    float*          PART  = (float*)(ws + 176160768);
    float*          ATT   = (float*)(ws + 176357376);
    unsigned short* W16   = (unsigned short*)(ws + 176361984);
    float*          DWT   = (float*)(ws + 176632320);             // ends 176,670,336
    unsigned short* ACC   = (unsigned short*)(ws + 176670720);    // 25,165,824 B

    const dim3 blk(256);

    wprep_k<<<dim3(566), blk, 0, stream>>>(
        qkv1_w, qkv2_w, mid1_w, mid2_w, pE_w, pE1_w, pE2_w, po1_w, po2_w,
        qkv1_dw, qkv2_dw, pE_dw, pE1_dw, pE2_dw, W16, DWT);

    // phase 1: qkv conv (fp32 NCHW input) + depthwise
    gemm_k<144,2,2,1,0,false><<<dim3(1024,1), blk, 0, stream>>>(
        nullptr, x1, 48, W16, QKVc1, 18, 0, nullptr, nullptr, nullptr);
    gemm_k<144,2,2,1,0,false><<<dim3(1024,1), blk, 0, stream>>>(
        nullptr, x2, 48, W16 + 9216, QKVc2, 18, 0, nullptr, nullptr, nullptr);
    dw144_k<<<dim3(2304,1,2), blk, 0, stream>>>(QKVc1, Q1, QKVc2, Q2, DWT);

    // phase 2: fused norms+dots, softmax
    attnA_k<<<dim3(32,16,2), blk, 0, stream>>>(Q1, Q2, PART);
    attnB_k<<<dim3(32), dim3(64), 0, stream>>>(PART, t1, t2, ATT);

    // phase 3+4: attn-out + mid conv + residual -> D16p (both branches)
    mid_k<<<dim3(512,2), blk, 0, stream>>>(Q1, Q2, ATT, x1, x2, W16 + 18432, D16p);

    // phase 5: gated FFN tail per branch (GH gemm, then fused dw+gelu+po)
    for (int br = 0; br < 2; br++) {
        gemm_k<96,3,2,0,0,true><<<dim3(4,1024), blk, 0, stream>>>(
            D16p, nullptr, 0, W16 + 24576 + br * 36864, GH, 48, 0,
            nullptr, nullptr, nullptr);
        if (br == 0)
            dwpo_k<0><<<dim3(2048), dim3(384), 0, stream>>>(
                GH, DWT + 2592, DWT + 6048, W16 + 98304,
                ACC, nullptr, nullptr, nullptr);
        else
            dwpo_k<3><<<dim3(2048), dim3(384), 0, stream>>>(
                GH, DWT + 2592 + 192, DWT + 7776, W16 + 116736,
                nullptr, dout, D16p, ACC);
    }
}

// Round 16
// 404.656 us; speedup vs baseline: 1.0068x; 1.0068x over previous
//
#include <hip/hip_runtime.h>
#include <math.h>

#define HW_ 65536

typedef __attribute__((ext_vector_type(8))) short b16x8;
typedef __attribute__((ext_vector_type(4))) short b16x4;
typedef __attribute__((ext_vector_type(4))) float f32x4;

__device__ __forceinline__ unsigned short f2b(float f) {
    union { float f; unsigned u; } v; v.f = f;
    unsigned r = v.u + 0x7fffu + ((v.u >> 16) & 1u);
    return (unsigned short)(r >> 16);
}
__device__ __forceinline__ float b2f(unsigned short h) {
    union { unsigned u; float f; } v; v.u = ((unsigned)h) << 16; return v.f;
}
__device__ __forceinline__ float gelu_f(float x) {
    float t = 0.7978845608f * fmaf(0.044715f * x, x * x, x);
    float e = __expf(2.f * t);
    float th = 1.f - 2.f / (e + 1.f);
    return 0.5f * x * (1.f + th);
}

__device__ __forceinline__ float wave_reduce_sum(float v) {
    #pragma unroll
    for (int off = 32; off; off >>= 1) v += __shfl_down(v, off, 64);
    return v;
}

// Blocked bf16 layout: element (px, ch) of a CC*8-channel tensor lives at
//   ((px>>4)*CC + (ch>>3))*128 + (px&15)*8 + (ch&7)
__device__ __forceinline__ size_t baddr(long px, int CC, int g) {
    return (((size_t)(px >> 4)) * CC + g) * 128 + ((size_t)(px & 15) << 3);
}

// ---------------------------------------------------------------------------
// Weight prep.
// ---------------------------------------------------------------------------
__global__ __launch_bounds__(256) void wprep_k(
    const float* __restrict__ q1w, const float* __restrict__ q2w,
    const float* __restrict__ m1w, const float* __restrict__ m2w,
    const float* __restrict__ pEw, const float* __restrict__ p1w,
    const float* __restrict__ p2w, const float* __restrict__ o1w,
    const float* __restrict__ o2w,
    const float* __restrict__ q1dw, const float* __restrict__ q2dw,
    const float* __restrict__ pEdw, const float* __restrict__ p1dw,
    const float* __restrict__ p2dw,
    unsigned short* __restrict__ wt, float* __restrict__ dwt)
{
    const int idx = blockIdx.x * 256 + threadIdx.x;
    if (idx < 135168) {
        const int base[8] = {0,9216,18432,21504,24576,61440,98304,116736};
        int s = 0;
        #pragma unroll
        for (int i = 1; i < 8; i++) if (idx >= base[i]) s = i;
        const int local = idx - base[s];
        float v = 0.f;
        if (s < 4) {
            const int m = local >> 6, k = local & 63;
            const float* src = (s == 0) ? q1w : (s == 1) ? q2w : (s == 2) ? m1w : m2w;
            if (k < 48) v = src[m * 48 + k];
        } else if (s < 6) {
            const int br = s - 4;
            const int m = local / 96, k = local % 96;
            if (m < 192) {
                v = pEw[(size_t)(br * 192 + m) * 96 + k];
            } else {
                const float* p12 = br ? p2w : p1w;
                const int lo = br * 48, m2 = m - 192;
                if (k >= lo && k < lo + 48) v = p12[m2 * 48 + (k - lo)];
            }
        } else {
            const int m = local / 192, k = local % 192;
            v = ((s == 6) ? o1w : o2w)[m * 192 + k];
        }
        wt[idx] = f2b(v);
    } else if (idx < 135168 + 9504) {
        const int d = idx - 135168;
        const int dbase[5] = {0,1296,2592,6048,7776};
        const int Cs[5] = {144,144,384,192,192};
        int s = 0;
        #pragma unroll
        for (int i = 1; i < 5; i++) if (d >= dbase[i]) s = i;
        const int local = d - dbase[s], C = Cs[s];
        const int t = local / C, c = local % C;
        const float* src = (s == 0) ? q1dw : (s == 1) ? q2dw : (s == 2) ? pEdw
                         : (s == 3) ? p1dw : p2dw;
        dwt[d] = src[c * 9 + t];
    }
}

// ---------------------------------------------------------------------------
// MFMA GEMM. EPI 0: blocked bf16 store. EPI 1: dout = res + acc.
// EPI 2: dout += acc. EPI 3: dout = b2f(res) + b2f(acc16) + acc.
// ---------------------------------------------------------------------------
template<int BM, int KC, int NT, int BSRC, int EPI, bool GRIDSWAP>
__global__ __launch_bounds__(256) void gemm_k(
    const unsigned short* __restrict__ B16,
    const float* __restrict__ Bf32, int Cin,
    const unsigned short* __restrict__ W16,
    unsigned short* __restrict__ out16, int CCo, int Coff,
    float* __restrict__ outf, const unsigned short* __restrict__ res,
    const unsigned short* __restrict__ acc16)
{
    constexpr int MF = BM / 16;
    const int tid = threadIdx.x;
    const int lane = tid & 63, w = tid >> 6;
    const int lm = lane & 15, lk = lane >> 4;
    const int mb = GRIDSWAP ? blockIdx.x : blockIdx.y;
    const int pxblk = GRIDSWAP ? blockIdx.y : blockIdx.x;
    const int m0 = mb * BM;
    const long wavepx = ((long)pxblk * 4 + w) * (NT * 16);
    const long pxb0 = wavepx >> 4;

    f32x4 acc[NT][MF];
    #pragma unroll
    for (int nt = 0; nt < NT; nt++)
        #pragma unroll
        for (int m = 0; m < MF; m++)
            #pragma unroll
            for (int j = 0; j < 4; j++) acc[nt][m][j] = 0.f;

    #pragma unroll
    for (int kc = 0; kc < KC; kc++) {
        b16x8 a[MF];
        #pragma unroll
        for (int m = 0; m < MF; m++)
            a[m] = *(const b16x8*)&W16[(size_t)(m0 + m * 16 + lm) * (KC * 32) + kc * 32 + lk * 8];
        #pragma unroll
        for (int nt = 0; nt < NT; nt++) {
            b16x8 bb;
            if (BSRC == 0) {
                bb = *(const b16x8*)&B16[((pxb0 + nt) * (KC * 4) + (kc * 4 + lk)) * 128 + lm * 8];
            } else {
                const long px = wavepx + nt * 16 + lm;
                const int p = (int)(px & 65535), bat = (int)(px >> 16);
                #pragma unroll
                for (int j = 0; j < 8; j++) {
                    const int c = kc * 32 + lk * 8 + j;
                    float v = (c < Cin) ? Bf32[((size_t)(bat * Cin + c) << 16) + p] : 0.f;
                    bb[j] = (short)f2b(v);
                }
            }
            #pragma unroll
            for (int m = 0; m < MF; m++)
                acc[nt][m] = __builtin_amdgcn_mfma_f32_16x16x32_bf16(a[m], bb, acc[nt][m], 0, 0, 0);
        }
    }

    #pragma unroll
    for (int nt = 0; nt < NT; nt++) {
        const long px = wavepx + nt * 16 + lm;
        #pragma unroll
        for (int m = 0; m < MF; m++) {
            const int mrow = m * 16 + lk * 4;
            if (EPI == 0) {
                b16x4 o;
                #pragma unroll
                for (int j = 0; j < 4; j++) o[j] = (short)f2b(acc[nt][m][j]);
                const int ch = Coff + m0 + mrow;
                *(b16x4*)&out16[((pxb0 + nt) * CCo + (ch >> 3)) * 128 + lm * 8 + (ch & 7)] = o;
            } else if (EPI == 1) {
                const int p = (int)(px & 65535), bat = (int)(px >> 16);
                b16x4 r4 = *(const b16x4*)&res[((pxb0 + nt) * 12 + (mrow >> 3)) * 128 + lm * 8 + (mrow & 7)];
                #pragma unroll
                for (int j = 0; j < 4; j++)
                    outf[((size_t)(bat * 96 + mrow + j) << 16) + p]
                        = acc[nt][m][j] + b2f((unsigned short)r4[j]);
            } else if (EPI == 2) {
                const int p = (int)(px & 65535), bat = (int)(px >> 16);
                #pragma unroll
                for (int j = 0; j < 4; j++) {
                    const size_t adr = ((size_t)(bat * 96 + mrow + j) << 16) + p;
                    outf[adr] += acc[nt][m][j];
                }
            } else {
                const int p = (int)(px & 65535), bat = (int)(px >> 16);
                const size_t boffi = ((pxb0 + nt) * 12 + (mrow >> 3)) * 128 + lm * 8 + (mrow & 7);
                b16x4 r4 = *(const b16x4*)&res[boffi];
                b16x4 a4 = *(const b16x4*)&acc16[boffi];
                #pragma unroll
                for (int j = 0; j < 4; j++)
                    outf[((size_t)(bat * 96 + mrow + j) << 16) + p]
                        = acc[nt][m][j] + b2f((unsigned short)r4[j]) + b2f((unsigned short)a4[j]);
            }
        }
    }
}

// ---------------------------------------------------------------------------
// dw 4px row core with static addressing (proven on dw144).
// ---------------------------------------------------------------------------
__device__ __forceinline__ void unpack8(const uint4 u, float f[8]) {
    union { unsigned u; float f; } a;
    a.u = u.x << 16;         f[0] = a.f;
    a.u = u.x & 0xFFFF0000u; f[1] = a.f;
    a.u = u.y << 16;         f[2] = a.f;
    a.u = u.y & 0xFFFF0000u; f[3] = a.f;
    a.u = u.z << 16;         f[4] = a.f;
    a.u = u.z & 0xFFFF0000u; f[5] = a.f;
    a.u = u.w << 16;         f[6] = a.f;
    a.u = u.w & 0xFFFF0000u; f[7] = a.f;
}

__device__ __forceinline__ void dw_row4(
    float acc[4][8], const unsigned short* __restrict__ T,
    size_t cb, long lOff, long rOff, bool lval, bool rval,
    const float* __restrict__ wrow, int wstr)
{
    float w[3][8];
    #pragma unroll
    for (int tx = 0; tx < 3; tx++) {
        const float4 a = *(const float4*)(wrow + (size_t)tx * wstr);
        const float4 b = *(const float4*)(wrow + (size_t)tx * wstr + 4);
        w[tx][0] = a.x; w[tx][1] = a.y; w[tx][2] = a.z; w[tx][3] = a.w;
        w[tx][4] = b.x; w[tx][5] = b.y; w[tx][6] = b.z; w[tx][7] = b.w;
    }
    uint4 u[6];
    if (lval) u[0] = *(const uint4*)&T[cb + lOff];
    else      u[0] = make_uint4(0u, 0u, 0u, 0u);
    #pragma unroll
    for (int c = 0; c < 4; c++) u[c + 1] = *(const uint4*)&T[cb + (size_t)c * 8];
    if (rval) u[5] = *(const uint4*)&T[cb + rOff];
    else      u[5] = make_uint4(0u, 0u, 0u, 0u);

    #pragma unroll
    for (int d = 0; d < 6; d++) {
        float f[8];
        unpack8(u[d], f);
        #pragma unroll
        for (int tx = 0; tx < 3; tx++) {
            const int p = d - tx;
            if (p >= 0 && p < 4)
                #pragma unroll
                for (int j = 0; j < 8; j++)
                    acc[p][j] = fmaf(w[tx][j], f[j], acc[p][j]);
        }
    }
}

// phase-1 depthwise: 144 ch (18 chunks), both branches via blockIdx.z.
__global__ __launch_bounds__(256) void dw144_k(
    const unsigned short* __restrict__ in1, unsigned short* __restrict__ out1,
    const unsigned short* __restrict__ in2, unsigned short* __restrict__ out2,
    const float* __restrict__ dwt)
{
    const int z = blockIdx.z;
    const unsigned short* in = z ? in2 : in1;
    unsigned short* out = z ? out2 : out1;
    const float* wt = dwt + z * 1296;
    const int bx = blockIdx.x;
    const int sb = (bx & 7) * 288 + (bx >> 3);
    const int idx = sb * 256 + threadIdx.x;   // < 589824
    const int pbi = idx / 72;
    const int rem = idx - pbi * 72;
    const int g = rem >> 2, i = rem & 3;
    const long px0 = (long)pbi * 16 + i * 4;
    const int x0 = (int)(px0 & 255);
    const int y = (int)((px0 >> 8) & 255);
    const bool lval = x0 > 0, rval = x0 < 252;
    const int off = (int)(px0 & 15) * 8;
    const size_t cb0 = ((size_t)(px0 >> 4) * 18 + g) * 128 + off;
    const long lOff = (off == 0) ? (120 - 18 * 128) : -8;
    const long rOff = (off == 96) ? (18 * 128 - 96) : 32;
    const long dyStep = 16 * 18 * 128;

    float acc[4][8];
    #pragma unroll
    for (int p = 0; p < 4; p++)
        #pragma unroll
        for (int j = 0; j < 8; j++) acc[p][j] = 0.f;

    #pragma unroll
    for (int dy = -1; dy <= 1; dy++) {
        const int yy = y + dy;
        if ((unsigned)yy >= 256u) continue;
        const size_t cb = cb0 + (size_t)((long)dy * dyStep);
        dw_row4(acc, in, cb, lOff, rOff, lval, rval,
                wt + g * 8 + (size_t)(dy + 1) * 3 * 144, 144);
    }

    #pragma unroll
    for (int p = 0; p < 4; p++) {
        b16x8 o;
        #pragma unroll
        for (int j = 0; j < 8; j++) o[j] = (short)f2b(acc[p][j]);
        *(b16x8*)&out[cb0 + (size_t)p * 8] = o;
    }
}

// ---------------------------------------------------------------------------
// dw 4px core (round-6 proven version — used by dwtail).
// ---------------------------------------------------------------------------
__device__ __forceinline__ void dw_acc8(
    float acc[4][8], const unsigned short* __restrict__ T, int CC, int g,
    long px0, int y, int x0, const float* __restrict__ wt, int wstr)
{
    #pragma unroll
    for (int dy = -1; dy <= 1; dy++) {
        const int yy = y + dy;
        if ((unsigned)yy >= 256u) continue;
        float w[3][8];
        #pragma unroll
        for (int t = 0; t < 3; t++) {
            const float* wp = wt + (size_t)((dy + 1) * 3 + t) * wstr;
            const float4 a = *(const float4*)wp;
            const float4 b = *(const float4*)(wp + 4);
            w[t][0] = a.x; w[t][1] = a.y; w[t][2] = a.z; w[t][3] = a.w;
            w[t][4] = b.x; w[t][5] = b.y; w[t][6] = b.z; w[t][7] = b.w;
        }
        #pragma unroll
        for (int c = 0; c < 6; c++) {
            const int xx = x0 - 1 + c;
            b16x8 v;
            if ((unsigned)xx < 256u) {
                v = *(const b16x8*)&T[baddr(px0 + dy * 256 + (c - 1), CC, g)];
            } else {
                #pragma unroll
                for (int k = 0; k < 8; k++) v[k] = 0;
            }
            float f[8];
            #pragma unroll
            for (int k = 0; k < 8; k++) f[k] = b2f((unsigned short)v[k]);
            const int ilo = (c - 2 < 0) ? 0 : c - 2;
            const int ihi = (c < 3) ? c : 3;
            #pragma unroll
            for (int i = ilo; i <= ihi; i++)
                #pragma unroll
                for (int j = 0; j < 8; j++)
                    acc[i][j] = fmaf(w[c - i][j], f[j], acc[i][j]);
        }
    }
}

// tail fused: Xg = gelu(dw(GH ch 0..191)) * dw(GH ch 192..383). blocked.
// Round-6 proven version (62 us): 4px x 8ch, default launch bounds.
__global__ __launch_bounds__(256) void dwtail_k(
    const unsigned short* __restrict__ GH, unsigned short* __restrict__ Xg,
    const float* __restrict__ dwtG, const float* __restrict__ dwtH)
{
    const int bx = blockIdx.x;
    const int sb = (bx & 7) * 384 + (bx >> 3);
    const int idx = sb * 256 + threadIdx.x;   // < 786432
    const int pb = idx / 96;
    const int rem = idx - pb * 96;
    const int g = rem >> 2, i = rem & 3;
    const long px0 = (long)pb * 16 + i * 4;
    const int y = (int)((px0 & 65535) >> 8), x0 = (int)(px0 & 255);

    float aG[4][8], aH[4][8];
    #pragma unroll
    for (int a = 0; a < 4; a++)
        #pragma unroll
        for (int j = 0; j < 8; j++) { aG[a][j] = 0.f; aH[a][j] = 0.f; }
    dw_acc8(aG, GH, 48, g,      px0, y, x0, dwtG + g * 8, 384);
    dw_acc8(aH, GH, 48, 24 + g, px0, y, x0, dwtH + g * 8, 192);

    #pragma unroll
    for (int a = 0; a < 4; a++) {
        b16x8 o;
        #pragma unroll
        for (int j = 0; j < 8; j++)
            o[j] = (short)f2b(gelu_f(aG[a][j]) * aH[a][j]);
        *(b16x8*)&Xg[baddr(px0 + a, 24, g)] = o;
    }
}

// ---------------------------------------------------------------------------
// Attention stage A.
// ---------------------------------------------------------------------------
__global__ __launch_bounds__(256) void attnA_k(
    const unsigned short* __restrict__ Q1, const unsigned short* __restrict__ Q2,
    float* __restrict__ part)
{
    const int tid = threadIdx.x;
    const int chunk = blockIdx.x, bh = blockIdx.y, a = blockIdx.z;
    const int b = bh >> 3, h = bh & 7;
    const unsigned* Qq = (const unsigned*)(a ? Q1 : Q2);
    const unsigned* Qk = (const unsigned*)(a ? Q2 : Q1);
    const int u0 = h * 3;
    const int cq = u0 >> 2, o = u0 & 3;
    const int ck = (24 + u0) >> 2;

    float dot[36], nq[6], nk[6];
    #pragma unroll
    for (int i = 0; i < 36; i++) dot[i] = 0.f;
    #pragma unroll
    for (int i = 0; i < 6; i++) { nq[i] = 0.f; nk[i] = 0.f; }

    #pragma unroll 1
    for (int r = 0; r < 8; r++) {
        const long px = (long)b * 65536 + chunk * 2048 + r * 256 + tid;
        const size_t rowu = ((size_t)(px >> 4)) * 18 * 64 + ((px & 15) << 2);
        const uint4 qa = *(const uint4*)&Qq[rowu + (size_t)cq * 64];
        const uint4 qb = *(const uint4*)&Qq[rowu + (size_t)(cq + 1) * 64];
        const uint4 ka = *(const uint4*)&Qk[rowu + (size_t)ck * 64];
        const uint4 kb = *(const uint4*)&Qk[rowu + (size_t)(ck + 1) * 64];
        unsigned uq[3], uk[3];
        if (o == 0)      { uq[0]=qa.x; uq[1]=qa.y; uq[2]=qa.z; uk[0]=ka.x; uk[1]=ka.y; uk[2]=ka.z; }
        else if (o == 1) { uq[0]=qa.y; uq[1]=qa.z; uq[2]=qa.w; uk[0]=ka.y; uk[1]=ka.z; uk[2]=ka.w; }
        else if (o == 2) { uq[0]=qa.z; uq[1]=qa.w; uq[2]=qb.x; uk[0]=ka.z; uk[1]=ka.w; uk[2]=kb.x; }
        else             { uq[0]=qa.w; uq[1]=qb.x; uq[2]=qb.y; uk[0]=ka.w; uk[1]=kb.x; uk[2]=kb.y; }
        float q[6], k[6];
        #pragma unroll
        for (int i = 0; i < 3; i++) {
            union { unsigned u; float f; } lo, hi;
            lo.u = uq[i] << 16; hi.u = uq[i] & 0xFFFF0000u;
            q[2 * i] = lo.f; q[2 * i + 1] = hi.f;
            lo.u = uk[i] << 16; hi.u = uk[i] & 0xFFFF0000u;
            k[2 * i] = lo.f; k[2 * i + 1] = hi.f;
        }
        #pragma unroll
        for (int c = 0; c < 6; c++) nq[c] = fmaf(q[c], q[c], nq[c]);
        #pragma unroll
        for (int d = 0; d < 6; d++) nk[d] = fmaf(k[d], k[d], nk[d]);
        #pragma unroll
        for (int c = 0; c < 6; c++)
            #pragma unroll
            for (int d = 0; d < 6; d++) dot[c * 6 + d] = fmaf(q[c], k[d], dot[c * 6 + d]);
    }

    __shared__ float red[4][48];
    const int lane = tid & 63, wid = tid >> 6;
    #pragma unroll
    for (int i = 0; i < 48; i++) {
        float v = (i < 36) ? dot[i] : (i < 42 ? nq[i - 36] : nk[i - 42]);
        v = wave_reduce_sum(v);
        if (!lane) red[wid][i] = v;
    }
    __syncthreads();
    if (tid < 48)
        part[((size_t)((a * 16 + bh) * 32 + chunk)) * 48 + tid]
            = red[0][tid] + red[1][tid] + red[2][tid] + red[3][tid];
}

__global__ void attnB_k(const float* __restrict__ part,
                        const float* __restrict__ t1, const float* __restrict__ t2,
                        float* __restrict__ att)
{
    const int abh = blockIdx.x, tid = threadIdx.x;
    const int a = abh >> 4, b = (abh >> 3) & 1, h = abh & 7;
    __shared__ float s[48];
    if (tid < 48) {
        float v = 0.f;
        for (int ch = 0; ch < 32; ch++) v += part[((size_t)abh * 32 + ch) * 48 + tid];
        s[tid] = v;
    }
    __syncthreads();
    if (tid < 6) {
        const int c = tid;
        const float tv = a ? t2[h] : t1[h];
        const float qn = fmaxf(sqrtf(s[36 + c]), 1e-12f);
        float raw[6];
        #pragma unroll
        for (int d = 0; d < 6; d++)
            raw[d] = tv * s[c * 6 + d] / (qn * fmaxf(sqrtf(s[42 + d]), 1e-12f));
        float m = raw[0];
        #pragma unroll
        for (int d = 1; d < 6; d++) m = fmaxf(m, raw[d]);
        float e[6], sum = 0.f;
        #pragma unroll
        for (int d = 0; d < 6; d++) { e[d] = expf(raw[d] - m); sum += e[d]; }
        const float inv = 1.f / sum;
        #pragma unroll
        for (int d = 0; d < 6; d++)
            att[((size_t)(a * 2 + b) * 8 + h) * 36 + c * 6 + d] = e[d] * inv;
    }
}

// ---------------------------------------------------------------------------
// Fused attn-out + mid conv + residual.
// ---------------------------------------------------------------------------
__global__ __launch_bounds__(256) void mid_k(
    const unsigned short* __restrict__ Q1, const unsigned short* __restrict__ Q2,
    const float* __restrict__ att,
    const float* __restrict__ x1, const float* __restrict__ x2,
    const unsigned short* __restrict__ Wm, unsigned short* __restrict__ D16p)
{
    const int br = blockIdx.y;
    const unsigned short* Qv = br ? Q2 : Q1;
    const float* x = br ? x2 : x1;
    const unsigned short* W16 = Wm + br * 3072;
    const float* attb = att + br * 576;
    const int boff = br * 48;

    __shared__ float atts[288];
    __shared__ unsigned short S[256][72];
    const int tid = threadIdx.x;
    const long px = (long)blockIdx.x * 256 + tid;
    const int bat = (int)(px >> 16);

    for (int i = tid; i < 288; i += 256) atts[i] = attb[bat * 288 + i];

    float v[48];
    #pragma unroll
    for (int i = 0; i < 6; i++) {
        b16x8 t = *(const b16x8*)&Qv[baddr(px, 18, 12 + i)];
        #pragma unroll
        for (int j = 0; j < 8; j++) v[i * 8 + j] = b2f((unsigned short)t[j]);
    }
    __syncthreads();

    #pragma unroll
    for (int h = 0; h < 8; h++) {
        unsigned short sh[6];
        #pragma unroll
        for (int c = 0; c < 6; c++) {
            float s = 0.f;
            #pragma unroll
            for (int d = 0; d < 6; d++) s = fmaf(atts[h * 36 + c * 6 + d], v[h * 6 + d], s);
            sh[c] = f2b(s);
        }
        #pragma unroll
        for (int i = 0; i < 3; i++) {
            unsigned packed = (unsigned)sh[2 * i] | ((unsigned)sh[2 * i + 1] << 16);
            *(unsigned*)&S[tid][h * 6 + 2 * i] = packed;
        }
    }
    #pragma unroll
    for (int i = 0; i < 8; i++) *(unsigned*)&S[tid][48 + 2 * i] = 0u;
    __syncthreads();

    const int lane = tid & 63, w = tid >> 6;
    const int lm = lane & 15, lk = lane >> 4;
    f32x4 acc[4][3];
    #pragma unroll
    for (int nt = 0; nt < 4; nt++)
        #pragma unroll
        for (int m = 0; m < 3; m++)
            #pragma unroll
            for (int j = 0; j < 4; j++) acc[nt][m][j] = 0.f;

    #pragma unroll
    for (int kc = 0; kc < 2; kc++) {
        b16x8 a[3];
        #pragma unroll
        for (int m = 0; m < 3; m++)
            a[m] = *(const b16x8*)&W16[(size_t)(m * 16 + lm) * 64 + kc * 32 + lk * 8];
        #pragma unroll
        for (int nt = 0; nt < 4; nt++) {
            b16x8 bb = *(const b16x8*)&S[w * 64 + nt * 16 + lm][kc * 32 + lk * 8];
            #pragma unroll
            for (int m = 0; m < 3; m++)
                acc[nt][m] = __builtin_amdgcn_mfma_f32_16x16x32_bf16(a[m], bb, acc[nt][m], 0, 0, 0);
        }
    }

    #pragma unroll
    for (int nt = 0; nt < 4; nt++) {
        const long px2 = (long)blockIdx.x * 256 + w * 64 + nt * 16 + lm;
        const int p2 = (int)(px2 & 65535);
        const long pxb2 = px2 >> 4;
        #pragma unroll
        for (int m = 0; m < 3; m++) {
            const int row = m * 16 + lk * 4;
            b16x4 o;
            #pragma unroll
            for (int j = 0; j < 4; j++) {
                float xv = x[((size_t)(bat * 48 + row + j) << 16) + p2];
                o[j] = (short)f2b(acc[nt][m][j] + xv);
            }
            const int ch = boff + row;
            *(b16x4*)&D16p[(pxb2 * 12 + (ch >> 3)) * 128 + lm * 8 + (ch & 7)] = o;
        }
    }
}

extern "C" void kernel_launch(void* const* d_in, const int* in_sizes, int n_in,
                              void* d_out, int out_size, void* d_ws, size_t ws_size,
                              hipStream_t stream) {
    const float* x1      = (const float*)d_in[0];
    const float* x2      = (const float*)d_in[1];
    const float* t1      = (const float*)d_in[2];
    const float* t2      = (const float*)d_in[3];
    const float* qkv1_w  = (const float*)d_in[4];
    const float* qkv1_dw = (const float*)d_in[5];
    const float* qkv2_w  = (const float*)d_in[6];
    const float* qkv2_dw = (const float*)d_in[7];
    const float* mid1_w  = (const float*)d_in[8];
    const float* mid2_w  = (const float*)d_in[9];
    const float* pE_w    = (const float*)d_in[10];
    const float* pE_dw   = (const float*)d_in[11];
    const float* pE1_w   = (const float*)d_in[12];
    const float* pE1_dw  = (const float*)d_in[13];
    const float* pE2_w   = (const float*)d_in[14];
    const float* pE2_dw  = (const float*)d_in[15];
    const float* po1_w   = (const float*)d_in[16];
    const float* po2_w   = (const float*)d_in[17];
    float* dout = (float*)d_out;
    char* ws = (char*)d_ws;

    // workspace layout (bytes); peak ~201.8 MB
    unsigned short* D16p  = (unsigned short*)(ws + 0);
    unsigned short* QKVc1 = (unsigned short*)(ws + 25165824);
    unsigned short* QKVc2 = (unsigned short*)(ws + 62914560);
    unsigned short* Q1    = (unsigned short*)(ws + 100663296);
    unsigned short* Q2    = (unsigned short*)(ws + 138412032);
    unsigned short* GH    = (unsigned short*)(ws + 25165824);     // phase5 overlay
    unsigned short* Xg    = (unsigned short*)(ws + 125829120);    // phase5 overlay
    float*          PART  = (float*)(ws + 176160768);
    float*          ATT   = (float*)(ws + 176357376);
    unsigned short* W16   = (unsigned short*)(ws + 176361984);
    float*          DWT   = (float*)(ws + 176632320);             // ends 176,670,336
    unsigned short* ACC   = (unsigned short*)(ws + 176670720);    // 25,165,824 B

    const dim3 blk(256);

    wprep_k<<<dim3(566), blk, 0, stream>>>(
        qkv1_w, qkv2_w, mid1_w, mid2_w, pE_w, pE1_w, pE2_w, po1_w, po2_w,
        qkv1_dw, qkv2_dw, pE_dw, pE1_dw, pE2_dw, W16, DWT);

    // phase 1: qkv conv (fp32 NCHW input) + depthwise
    gemm_k<144,2,2,1,0,false><<<dim3(1024,1), blk, 0, stream>>>(
        nullptr, x1, 48, W16, QKVc1, 18, 0, nullptr, nullptr, nullptr);
    gemm_k<144,2,2,1,0,false><<<dim3(1024,1), blk, 0, stream>>>(
        nullptr, x2, 48, W16 + 9216, QKVc2, 18, 0, nullptr, nullptr, nullptr);
    dw144_k<<<dim3(2304,1,2), blk, 0, stream>>>(QKVc1, Q1, QKVc2, Q2, DWT);

    // phase 2: fused norms+dots, softmax
    attnA_k<<<dim3(32,16,2), blk, 0, stream>>>(Q1, Q2, PART);
    attnB_k<<<dim3(32), dim3(64), 0, stream>>>(PART, t1, t2, ATT);

    // phase 3+4: attn-out + mid conv + residual -> D16p (both branches)
    mid_k<<<dim3(512,2), blk, 0, stream>>>(Q1, Q2, ATT, x1, x2, W16 + 18432, D16p);

    // phase 5: gated FFN tail per branch
    for (int br = 0; br < 2; br++) {
        gemm_k<96,3,2,0,0,true><<<dim3(4,1024), blk, 0, stream>>>(
            D16p, nullptr, 0, W16 + 24576 + br * 36864, GH, 48, 0,
            nullptr, nullptr, nullptr);
        dwtail_k<<<dim3(3072), blk, 0, stream>>>(
            GH, Xg, DWT + 2592 + br * 192, DWT + (br ? 7776 : 6048));
        if (br == 0)
            gemm_k<96,6,2,0,0,false><<<dim3(1024,1), blk, 0, stream>>>(
                Xg, nullptr, 0, W16 + 98304, ACC, 12, 0, nullptr, nullptr, nullptr);
        else
            gemm_k<96,6,2,0,3,false><<<dim3(1024,1), blk, 0, stream>>>(
                Xg, nullptr, 0, W16 + 116736, nullptr, 0, 0, dout, D16p, ACC);
    }
}

// Round 17
// 394.042 us; speedup vs baseline: 1.0340x; 1.0269x over previous
//
#include <hip/hip_runtime.h>
#include <math.h>

#define HW_ 65536

typedef __attribute__((ext_vector_type(8))) short b16x8;
typedef __attribute__((ext_vector_type(4))) short b16x4;
typedef __attribute__((ext_vector_type(4))) float f32x4;
typedef __attribute__((ext_vector_type(2))) float f32x2;

__device__ __forceinline__ unsigned short f2b(float f) {
    union { float f; unsigned u; } v; v.f = f;
    unsigned r = v.u + 0x7fffu + ((v.u >> 16) & 1u);
    return (unsigned short)(r >> 16);
}
__device__ __forceinline__ float b2f(unsigned short h) {
    union { unsigned u; float f; } v; v.u = ((unsigned)h) << 16; return v.f;
}
__device__ __forceinline__ float gelu_f(float x) {
    float t = 0.7978845608f * fmaf(0.044715f * x, x * x, x);
    float e = __expf(2.f * t);
    float th = 1.f - 2.f / (e + 1.f);
    return 0.5f * x * (1.f + th);
}

// packed dual-fma: v_pk_fma_f32 on CDNA (falls back to scalar if unavailable)
__device__ __forceinline__ f32x2 pk_fma(f32x2 a, f32x2 b, f32x2 c) {
#if __has_builtin(__builtin_elementwise_fma)
    return __builtin_elementwise_fma(a, b, c);
#else
    f32x2 r; r[0] = fmaf(a[0], b[0], c[0]); r[1] = fmaf(a[1], b[1], c[1]);
    return r;
#endif
}

__device__ __forceinline__ float wave_reduce_sum(float v) {
    #pragma unroll
    for (int off = 32; off; off >>= 1) v += __shfl_down(v, off, 64);
    return v;
}

// Blocked bf16 layout: element (px, ch) of a CC*8-channel tensor lives at
//   ((px>>4)*CC + (ch>>3))*128 + (px&15)*8 + (ch&7)
__device__ __forceinline__ size_t baddr(long px, int CC, int g) {
    return (((size_t)(px >> 4)) * CC + g) * 128 + ((size_t)(px & 15) << 3);
}

// ---------------------------------------------------------------------------
// Weight prep (unchanged).
// ---------------------------------------------------------------------------
__global__ __launch_bounds__(256) void wprep_k(
    const float* __restrict__ q1w, const float* __restrict__ q2w,
    const float* __restrict__ m1w, const float* __restrict__ m2w,
    const float* __restrict__ pEw, const float* __restrict__ p1w,
    const float* __restrict__ p2w, const float* __restrict__ o1w,
    const float* __restrict__ o2w,
    const float* __restrict__ q1dw, const float* __restrict__ q2dw,
    const float* __restrict__ pEdw, const float* __restrict__ p1dw,
    const float* __restrict__ p2dw,
    unsigned short* __restrict__ wt, float* __restrict__ dwt)
{
    const int idx = blockIdx.x * 256 + threadIdx.x;
    if (idx < 135168) {
        const int base[8] = {0,9216,18432,21504,24576,61440,98304,116736};
        int s = 0;
        #pragma unroll
        for (int i = 1; i < 8; i++) if (idx >= base[i]) s = i;
        const int local = idx - base[s];
        float v = 0.f;
        if (s < 4) {
            const int m = local >> 6, k = local & 63;
            const float* src = (s == 0) ? q1w : (s == 1) ? q2w : (s == 2) ? m1w : m2w;
            if (k < 48) v = src[m * 48 + k];
        } else if (s < 6) {
            const int br = s - 4;
            const int m = local / 96, k = local % 96;
            if (m < 192) {
                v = pEw[(size_t)(br * 192 + m) * 96 + k];
            } else {
                const float* p12 = br ? p2w : p1w;
                const int lo = br * 48, m2 = m - 192;
                if (k >= lo && k < lo + 48) v = p12[m2 * 48 + (k - lo)];
            }
        } else {
            const int m = local / 192, k = local % 192;
            v = ((s == 6) ? o1w : o2w)[m * 192 + k];
        }
        wt[idx] = f2b(v);
    } else if (idx < 135168 + 9504) {
        const int d = idx - 135168;
        const int dbase[5] = {0,1296,2592,6048,7776};
        const int Cs[5] = {144,144,384,192,192};
        int s = 0;
        #pragma unroll
        for (int i = 1; i < 5; i++) if (d >= dbase[i]) s = i;
        const int local = d - dbase[s], C = Cs[s];
        const int t = local / C, c = local % C;
        const float* src = (s == 0) ? q1dw : (s == 1) ? q2dw : (s == 2) ? pEdw
                         : (s == 3) ? p1dw : p2dw;
        dwt[d] = src[c * 9 + t];
    }
}

// ---------------------------------------------------------------------------
// MFMA GEMM (unchanged from r13).
// ---------------------------------------------------------------------------
template<int BM, int KC, int NT, int BSRC, int EPI, bool GRIDSWAP>
__global__ __launch_bounds__(256) void gemm_k(
    const unsigned short* __restrict__ B16,
    const float* __restrict__ Bf32, int Cin,
    const unsigned short* __restrict__ W16,
    unsigned short* __restrict__ out16, int CCo, int Coff,
    float* __restrict__ outf, const unsigned short* __restrict__ res,
    const unsigned short* __restrict__ acc16)
{
    constexpr int MF = BM / 16;
    const int tid = threadIdx.x;
    const int lane = tid & 63, w = tid >> 6;
    const int lm = lane & 15, lk = lane >> 4;
    const int mb = GRIDSWAP ? blockIdx.x : blockIdx.y;
    const int pxblk = GRIDSWAP ? blockIdx.y : blockIdx.x;
    const int m0 = mb * BM;
    const long wavepx = ((long)pxblk * 4 + w) * (NT * 16);
    const long pxb0 = wavepx >> 4;

    f32x4 acc[NT][MF];
    #pragma unroll
    for (int nt = 0; nt < NT; nt++)
        #pragma unroll
        for (int m = 0; m < MF; m++)
            #pragma unroll
            for (int j = 0; j < 4; j++) acc[nt][m][j] = 0.f;

    #pragma unroll
    for (int kc = 0; kc < KC; kc++) {
        b16x8 a[MF];
        #pragma unroll
        for (int m = 0; m < MF; m++)
            a[m] = *(const b16x8*)&W16[(size_t)(m0 + m * 16 + lm) * (KC * 32) + kc * 32 + lk * 8];
        #pragma unroll
        for (int nt = 0; nt < NT; nt++) {
            b16x8 bb;
            if (BSRC == 0) {
                bb = *(const b16x8*)&B16[((pxb0 + nt) * (KC * 4) + (kc * 4 + lk)) * 128 + lm * 8];
            } else {
                const long px = wavepx + nt * 16 + lm;
                const int p = (int)(px & 65535), bat = (int)(px >> 16);
                #pragma unroll
                for (int j = 0; j < 8; j++) {
                    const int c = kc * 32 + lk * 8 + j;
                    float v = (c < Cin) ? Bf32[((size_t)(bat * Cin + c) << 16) + p] : 0.f;
                    bb[j] = (short)f2b(v);
                }
            }
            #pragma unroll
            for (int m = 0; m < MF; m++)
                acc[nt][m] = __builtin_amdgcn_mfma_f32_16x16x32_bf16(a[m], bb, acc[nt][m], 0, 0, 0);
        }
    }

    #pragma unroll
    for (int nt = 0; nt < NT; nt++) {
        const long px = wavepx + nt * 16 + lm;
        #pragma unroll
        for (int m = 0; m < MF; m++) {
            const int mrow = m * 16 + lk * 4;
            if (EPI == 0) {
                b16x4 o;
                #pragma unroll
                for (int j = 0; j < 4; j++) o[j] = (short)f2b(acc[nt][m][j]);
                const int ch = Coff + m0 + mrow;
                *(b16x4*)&out16[((pxb0 + nt) * CCo + (ch >> 3)) * 128 + lm * 8 + (ch & 7)] = o;
            } else if (EPI == 1) {
                const int p = (int)(px & 65535), bat = (int)(px >> 16);
                b16x4 r4 = *(const b16x4*)&res[((pxb0 + nt) * 12 + (mrow >> 3)) * 128 + lm * 8 + (mrow & 7)];
                #pragma unroll
                for (int j = 0; j < 4; j++)
                    outf[((size_t)(bat * 96 + mrow + j) << 16) + p]
                        = acc[nt][m][j] + b2f((unsigned short)r4[j]);
            } else if (EPI == 2) {
                const int p = (int)(px & 65535), bat = (int)(px >> 16);
                #pragma unroll
                for (int j = 0; j < 4; j++) {
                    const size_t adr = ((size_t)(bat * 96 + mrow + j) << 16) + p;
                    outf[adr] += acc[nt][m][j];
                }
            } else {
                const int p = (int)(px & 65535), bat = (int)(px >> 16);
                const size_t boffi = ((pxb0 + nt) * 12 + (mrow >> 3)) * 128 + lm * 8 + (mrow & 7);
                b16x4 r4 = *(const b16x4*)&res[boffi];
                b16x4 a4 = *(const b16x4*)&acc16[boffi];
                #pragma unroll
                for (int j = 0; j < 4; j++)
                    outf[((size_t)(bat * 96 + mrow + j) << 16) + p]
                        = acc[nt][m][j] + b2f((unsigned short)r4[j]) + b2f((unsigned short)a4[j]);
            }
        }
    }
}

// ---------------------------------------------------------------------------
// Packed unpack: uint4 (8 bf16) -> 4 x f32x2.
// ---------------------------------------------------------------------------
__device__ __forceinline__ void unpack8v(const uint4 u, f32x2 f[4]) {
    union { unsigned u; float f; } a, b;
    a.u = u.x << 16; b.u = u.x & 0xFFFF0000u; f[0][0] = a.f; f[0][1] = b.f;
    a.u = u.y << 16; b.u = u.y & 0xFFFF0000u; f[1][0] = a.f; f[1][1] = b.f;
    a.u = u.z << 16; b.u = u.z & 0xFFFF0000u; f[2][0] = a.f; f[2][1] = b.f;
    a.u = u.w << 16; b.u = u.w & 0xFFFF0000u; f[3][0] = a.f; f[3][1] = b.f;
}

// ---------------------------------------------------------------------------
// dw 4px row core, static addressing + packed f32x2 FMAs (v_pk_fma_f32).
// ---------------------------------------------------------------------------
__device__ __forceinline__ void dw_row4(
    f32x2 acc[4][4], const unsigned short* __restrict__ T,
    size_t cb, long lOff, long rOff, bool lval, bool rval,
    const float* __restrict__ wrow, int wstr)
{
    f32x2 w[3][4];
    #pragma unroll
    for (int tx = 0; tx < 3; tx++) {
        const float4 a = *(const float4*)(wrow + (size_t)tx * wstr);
        const float4 b = *(const float4*)(wrow + (size_t)tx * wstr + 4);
        w[tx][0][0] = a.x; w[tx][0][1] = a.y;
        w[tx][1][0] = a.z; w[tx][1][1] = a.w;
        w[tx][2][0] = b.x; w[tx][2][1] = b.y;
        w[tx][3][0] = b.z; w[tx][3][1] = b.w;
    }
    uint4 u[6];
    if (lval) u[0] = *(const uint4*)&T[cb + lOff];
    else      u[0] = make_uint4(0u, 0u, 0u, 0u);
    #pragma unroll
    for (int c = 0; c < 4; c++) u[c + 1] = *(const uint4*)&T[cb + (size_t)c * 8];
    if (rval) u[5] = *(const uint4*)&T[cb + rOff];
    else      u[5] = make_uint4(0u, 0u, 0u, 0u);

    #pragma unroll
    for (int d = 0; d < 6; d++) {
        f32x2 f[4];
        unpack8v(u[d], f);
        #pragma unroll
        for (int tx = 0; tx < 3; tx++) {
            const int p = d - tx;
            if (p >= 0 && p < 4)
                #pragma unroll
                for (int q = 0; q < 4; q++)
                    acc[p][q] = pk_fma(w[tx][q], f[q], acc[p][q]);
        }
    }
}

// phase-1 depthwise: 144 ch (18 chunks), both branches via blockIdx.z.
__global__ __launch_bounds__(256) void dw144_k(
    const unsigned short* __restrict__ in1, unsigned short* __restrict__ out1,
    const unsigned short* __restrict__ in2, unsigned short* __restrict__ out2,
    const float* __restrict__ dwt)
{
    const int z = blockIdx.z;
    const unsigned short* in = z ? in2 : in1;
    unsigned short* out = z ? out2 : out1;
    const float* wt = dwt + z * 1296;
    const int bx = blockIdx.x;
    const int sb = (bx & 7) * 288 + (bx >> 3);
    const int idx = sb * 256 + threadIdx.x;   // < 589824
    const int pbi = idx / 72;
    const int rem = idx - pbi * 72;
    const int g = rem >> 2, i = rem & 3;
    const long px0 = (long)pbi * 16 + i * 4;
    const int x0 = (int)(px0 & 255);
    const int y = (int)((px0 >> 8) & 255);
    const bool lval = x0 > 0, rval = x0 < 252;
    const int off = (int)(px0 & 15) * 8;
    const size_t cb0 = ((size_t)(px0 >> 4) * 18 + g) * 128 + off;
    const long lOff = (off == 0) ? (120 - 18 * 128) : -8;
    const long rOff = (off == 96) ? (18 * 128 - 96) : 32;
    const long dyStep = 16 * 18 * 128;

    f32x2 acc[4][4];
    #pragma unroll
    for (int p = 0; p < 4; p++)
        #pragma unroll
        for (int q = 0; q < 4; q++) { acc[p][q][0] = 0.f; acc[p][q][1] = 0.f; }

    #pragma unroll
    for (int dy = -1; dy <= 1; dy++) {
        const int yy = y + dy;
        if ((unsigned)yy >= 256u) continue;
        const size_t cb = cb0 + (size_t)((long)dy * dyStep);
        dw_row4(acc, in, cb, lOff, rOff, lval, rval,
                wt + g * 8 + (size_t)(dy + 1) * 3 * 144, 144);
    }

    #pragma unroll
    for (int p = 0; p < 4; p++) {
        b16x8 o;
        #pragma unroll
        for (int j = 0; j < 8; j++) o[j] = (short)f2b(acc[p][j >> 1][j & 1]);
        *(b16x8*)&out[cb0 + (size_t)p * 8] = o;
    }
}

// tail fused: Xg = gelu(dw(GH ch 0..191)) * dw(GH ch 192..383). blocked.
// r13 structure (4px x 8ch, default launch bounds) + packed FMAs.
__global__ __launch_bounds__(256) void dwtail_k(
    const unsigned short* __restrict__ GH, unsigned short* __restrict__ Xg,
    const float* __restrict__ dwtG, const float* __restrict__ dwtH)
{
    const int bx = blockIdx.x;
    const int sb = (bx & 7) * 384 + (bx >> 3);
    const int idx = sb * 256 + threadIdx.x;   // < 786432
    const int pbi = idx / 96;
    const int rem = idx - pbi * 96;
    const int g = rem >> 2, i = rem & 3;
    const long px0 = (long)pbi * 16 + i * 4;
    const int x0 = (int)(px0 & 255);
    const int y = (int)((px0 >> 8) & 255);
    const bool lval = x0 > 0, rval = x0 < 252;
    const int off = (int)(px0 & 15) * 8;
    const size_t cb0 = ((size_t)(px0 >> 4) * 48 + g) * 128 + off;   // G base
    const long lOff = (off == 0) ? (120 - 48 * 128) : -8;
    const long rOff = (off == 96) ? (48 * 128 - 96) : 32;
    const long dyStep = 16 * 48 * 128;

    f32x2 aG[4][4], aH[4][4];
    #pragma unroll
    for (int p = 0; p < 4; p++)
        #pragma unroll
        for (int q = 0; q < 4; q++) {
            aG[p][q][0] = 0.f; aG[p][q][1] = 0.f;
            aH[p][q][0] = 0.f; aH[p][q][1] = 0.f;
        }

    #pragma unroll
    for (int dy = -1; dy <= 1; dy++) {
        const int yy = y + dy;
        if ((unsigned)yy >= 256u) continue;
        const size_t cb = cb0 + (size_t)((long)dy * dyStep);
        dw_row4(aG, GH, cb, lOff, rOff, lval, rval,
                dwtG + g * 8 + (size_t)(dy + 1) * 3 * 384, 384);
        dw_row4(aH, GH, cb + 3072, lOff, rOff, lval, rval,
                dwtH + g * 8 + (size_t)(dy + 1) * 3 * 192, 192);
    }

    const size_t ob = ((size_t)(px0 >> 4) * 24 + g) * 128 + off;
    #pragma unroll
    for (int p = 0; p < 4; p++) {
        b16x8 o;
        #pragma unroll
        for (int j = 0; j < 8; j++)
            o[j] = (short)f2b(gelu_f(aG[p][j >> 1][j & 1]) * aH[p][j >> 1][j & 1]);
        *(b16x8*)&Xg[ob + (size_t)p * 8] = o;
    }
}

// ---------------------------------------------------------------------------
// Attention stage A (unchanged).
// ---------------------------------------------------------------------------
__global__ __launch_bounds__(256) void attnA_k(
    const unsigned short* __restrict__ Q1, const unsigned short* __restrict__ Q2,
    float* __restrict__ part)
{
    const int tid = threadIdx.x;
    const int chunk = blockIdx.x, bh = blockIdx.y, a = blockIdx.z;
    const int b = bh >> 3, h = bh & 7;
    const unsigned* Qq = (const unsigned*)(a ? Q1 : Q2);
    const unsigned* Qk = (const unsigned*)(a ? Q2 : Q1);
    const int u0 = h * 3;
    const int cq = u0 >> 2, o = u0 & 3;
    const int ck = (24 + u0) >> 2;

    float dot[36], nq[6], nk[6];
    #pragma unroll
    for (int i = 0; i < 36; i++) dot[i] = 0.f;
    #pragma unroll
    for (int i = 0; i < 6; i++) { nq[i] = 0.f; nk[i] = 0.f; }

    #pragma unroll 1
    for (int r = 0; r < 8; r++) {
        const long px = (long)b * 65536 + chunk * 2048 + r * 256 + tid;
        const size_t rowu = ((size_t)(px >> 4)) * 18 * 64 + ((px & 15) << 2);
        const uint4 qa = *(const uint4*)&Qq[rowu + (size_t)cq * 64];
        const uint4 qb = *(const uint4*)&Qq[rowu + (size_t)(cq + 1) * 64];
        const uint4 ka = *(const uint4*)&Qk[rowu + (size_t)ck * 64];
        const uint4 kb = *(const uint4*)&Qk[rowu + (size_t)(ck + 1) * 64];
        unsigned uq[3], uk[3];
        if (o == 0)      { uq[0]=qa.x; uq[1]=qa.y; uq[2]=qa.z; uk[0]=ka.x; uk[1]=ka.y; uk[2]=ka.z; }
        else if (o == 1) { uq[0]=qa.y; uq[1]=qa.z; uq[2]=qa.w; uk[0]=ka.y; uk[1]=ka.z; uk[2]=ka.w; }
        else if (o == 2) { uq[0]=qa.z; uq[1]=qa.w; uq[2]=qb.x; uk[0]=ka.z; uk[1]=ka.w; uk[2]=kb.x; }
        else             { uq[0]=qa.w; uq[1]=qb.x; uq[2]=qb.y; uk[0]=ka.w; uk[1]=kb.x; uk[2]=kb.y; }
        float q[6], k[6];
        #pragma unroll
        for (int i = 0; i < 3; i++) {
            union { unsigned u; float f; } lo, hi;
            lo.u = uq[i] << 16; hi.u = uq[i] & 0xFFFF0000u;
            q[2 * i] = lo.f; q[2 * i + 1] = hi.f;
            lo.u = uk[i] << 16; hi.u = uk[i] & 0xFFFF0000u;
            k[2 * i] = lo.f; k[2 * i + 1] = hi.f;
        }
        #pragma unroll
        for (int c = 0; c < 6; c++) nq[c] = fmaf(q[c], q[c], nq[c]);
        #pragma unroll
        for (int d = 0; d < 6; d++) nk[d] = fmaf(k[d], k[d], nk[d]);
        #pragma unroll
        for (int c = 0; c < 6; c++)
            #pragma unroll
            for (int d = 0; d < 6; d++) dot[c * 6 + d] = fmaf(q[c], k[d], dot[c * 6 + d]);
    }

    __shared__ float red[4][48];
    const int lane = tid & 63, wid = tid >> 6;
    #pragma unroll
    for (int i = 0; i < 48; i++) {
        float v = (i < 36) ? dot[i] : (i < 42 ? nq[i - 36] : nk[i - 42]);
        v = wave_reduce_sum(v);
        if (!lane) red[wid][i] = v;
    }
    __syncthreads();
    if (tid < 48)
        part[((size_t)((a * 16 + bh) * 32 + chunk)) * 48 + tid]
            = red[0][tid] + red[1][tid] + red[2][tid] + red[3][tid];
}

__global__ void attnB_k(const float* __restrict__ part,
                        const float* __restrict__ t1, const float* __restrict__ t2,
                        float* __restrict__ att)
{
    const int abh = blockIdx.x, tid = threadIdx.x;
    const int a = abh >> 4, b = (abh >> 3) & 1, h = abh & 7;
    __shared__ float s[48];
    if (tid < 48) {
        float v = 0.f;
        for (int ch = 0; ch < 32; ch++) v += part[((size_t)abh * 32 + ch) * 48 + tid];
        s[tid] = v;
    }
    __syncthreads();
    if (tid < 6) {
        const int c = tid;
        const float tv = a ? t2[h] : t1[h];
        const float qn = fmaxf(sqrtf(s[36 + c]), 1e-12f);
        float raw[6];
        #pragma unroll
        for (int d = 0; d < 6; d++)
            raw[d] = tv * s[c * 6 + d] / (qn * fmaxf(sqrtf(s[42 + d]), 1e-12f));
        float m = raw[0];
        #pragma unroll
        for (int d = 1; d < 6; d++) m = fmaxf(m, raw[d]);
        float e[6], sum = 0.f;
        #pragma unroll
        for (int d = 0; d < 6; d++) { e[d] = expf(raw[d] - m); sum += e[d]; }
        const float inv = 1.f / sum;
        #pragma unroll
        for (int d = 0; d < 6; d++)
            att[((size_t)(a * 2 + b) * 8 + h) * 36 + c * 6 + d] = e[d] * inv;
    }
}

// ---------------------------------------------------------------------------
// Fused attn-out + mid conv + residual (unchanged).
// ---------------------------------------------------------------------------
__global__ __launch_bounds__(256) void mid_k(
    const unsigned short* __restrict__ Q1, const unsigned short* __restrict__ Q2,
    const float* __restrict__ att,
    const float* __restrict__ x1, const float* __restrict__ x2,
    const unsigned short* __restrict__ Wm, unsigned short* __restrict__ D16p)
{
    const int br = blockIdx.y;
    const unsigned short* Qv = br ? Q2 : Q1;
    const float* x = br ? x2 : x1;
    const unsigned short* W16 = Wm + br * 3072;
    const float* attb = att + br * 576;
    const int boff = br * 48;

    __shared__ float atts[288];
    __shared__ unsigned short S[256][72];
    const int tid = threadIdx.x;
    const long px = (long)blockIdx.x * 256 + tid;
    const int bat = (int)(px >> 16);

    for (int i = tid; i < 288; i += 256) atts[i] = attb[bat * 288 + i];

    float v[48];
    #pragma unroll
    for (int i = 0; i < 6; i++) {
        b16x8 t = *(const b16x8*)&Qv[baddr(px, 18, 12 + i)];
        #pragma unroll
        for (int j = 0; j < 8; j++) v[i * 8 + j] = b2f((unsigned short)t[j]);
    }
    __syncthreads();

    #pragma unroll
    for (int h = 0; h < 8; h++) {
        unsigned short sh[6];
        #pragma unroll
        for (int c = 0; c < 6; c++) {
            float s = 0.f;
            #pragma unroll
            for (int d = 0; d < 6; d++) s = fmaf(atts[h * 36 + c * 6 + d], v[h * 6 + d], s);
            sh[c] = f2b(s);
        }
        #pragma unroll
        for (int i = 0; i < 3; i++) {
            unsigned packed = (unsigned)sh[2 * i] | ((unsigned)sh[2 * i + 1] << 16);
            *(unsigned*)&S[tid][h * 6 + 2 * i] = packed;
        }
    }
    #pragma unroll
    for (int i = 0; i < 8; i++) *(unsigned*)&S[tid][48 + 2 * i] = 0u;
    __syncthreads();

    const int lane = tid & 63, w = tid >> 6;
    const int lm = lane & 15, lk = lane >> 4;
    f32x4 acc[4][3];
    #pragma unroll
    for (int nt = 0; nt < 4; nt++)
        #pragma unroll
        for (int m = 0; m < 3; m++)
            #pragma unroll
            for (int j = 0; j < 4; j++) acc[nt][m][j] = 0.f;

    #pragma unroll
    for (int kc = 0; kc < 2; kc++) {
        b16x8 a[3];
        #pragma unroll
        for (int m = 0; m < 3; m++)
            a[m] = *(const b16x8*)&W16[(size_t)(m * 16 + lm) * 64 + kc * 32 + lk * 8];
        #pragma unroll
        for (int nt = 0; nt < 4; nt++) {
            b16x8 bb = *(const b16x8*)&S[w * 64 + nt * 16 + lm][kc * 32 + lk * 8];
            #pragma unroll
            for (int m = 0; m < 3; m++)
                acc[nt][m] = __builtin_amdgcn_mfma_f32_16x16x32_bf16(a[m], bb, acc[nt][m], 0, 0, 0);
        }
    }

    #pragma unroll
    for (int nt = 0; nt < 4; nt++) {
        const long px2 = (long)blockIdx.x * 256 + w * 64 + nt * 16 + lm;
        const int p2 = (int)(px2 & 65535);
        const long pxb2 = px2 >> 4;
        #pragma unroll
        for (int m = 0; m < 3; m++) {
            const int row = m * 16 + lk * 4;
            b16x4 o;
            #pragma unroll
            for (int j = 0; j < 4; j++) {
                float xv = x[((size_t)(bat * 48 + row + j) << 16) + p2];
                o[j] = (short)f2b(acc[nt][m][j] + xv);
            }
            const int ch = boff + row;
            *(b16x4*)&D16p[(pxb2 * 12 + (ch >> 3)) * 128 + lm * 8 + (ch & 7)] = o;
        }
    }
}

extern "C" void kernel_launch(void* const* d_in, const int* in_sizes, int n_in,
                              void* d_out, int out_size, void* d_ws, size_t ws_size,
                              hipStream_t stream) {
    const float* x1      = (const float*)d_in[0];
    const float* x2      = (const float*)d_in[1];
    const float* t1      = (const float*)d_in[2];
    const float* t2      = (const float*)d_in[3];
    const float* qkv1_w  = (const float*)d_in[4];
    const float* qkv1_dw = (const float*)d_in[5];
    const float* qkv2_w  = (const float*)d_in[6];
    const float* qkv2_dw = (const float*)d_in[7];
    const float* mid1_w  = (const float*)d_in[8];
    const float* mid2_w  = (const float*)d_in[9];
    const float* pE_w    = (const float*)d_in[10];
    const float* pE_dw   = (const float*)d_in[11];
    const float* pE1_w   = (const float*)d_in[12];
    const float* pE1_dw  = (const float*)d_in[13];
    const float* pE2_w   = (const float*)d_in[14];
    const float* pE2_dw  = (const float*)d_in[15];
    const float* po1_w   = (const float*)d_in[16];
    const float* po2_w   = (const float*)d_in[17];
    float* dout = (float*)d_out;
    char* ws = (char*)d_ws;

    // workspace layout (bytes); peak ~201.8 MB
    unsigned short* D16p  = (unsigned short*)(ws + 0);
    unsigned short* QKVc1 = (unsigned short*)(ws + 25165824);
    unsigned short* QKVc2 = (unsigned short*)(ws + 62914560);
    unsigned short* Q1    = (unsigned short*)(ws + 100663296);
    unsigned short* Q2    = (unsigned short*)(ws + 138412032);
    unsigned short* GH    = (unsigned short*)(ws + 25165824);     // phase5 overlay
    unsigned short* Xg    = (unsigned short*)(ws + 125829120);    // phase5 overlay
    float*          PART  = (float*)(ws + 176160768);
    float*          ATT   = (float*)(ws + 176357376);
    unsigned short* W16   = (unsigned short*)(ws + 176361984);
    float*          DWT   = (float*)(ws + 176632320);             // ends 176,670,336
    unsigned short* ACC   = (unsigned short*)(ws + 176670720);    // 25,165,824 B

    const dim3 blk(256);

    wprep_k<<<dim3(566), blk, 0, stream>>>(
        qkv1_w, qkv2_w, mid1_w, mid2_w, pE_w, pE1_w, pE2_w, po1_w, po2_w,
        qkv1_dw, qkv2_dw, pE_dw, pE1_dw, pE2_dw, W16, DWT);

    // phase 1: qkv conv (fp32 NCHW input) + depthwise
    gemm_k<144,2,2,1,0,false><<<dim3(1024,1), blk, 0, stream>>>(
        nullptr, x1, 48, W16, QKVc1, 18, 0, nullptr, nullptr, nullptr);
    gemm_k<144,2,2,1,0,false><<<dim3(1024,1), blk, 0, stream>>>(
        nullptr, x2, 48, W16 + 9216, QKVc2, 18, 0, nullptr, nullptr, nullptr);
    dw144_k<<<dim3(2304,1,2), blk, 0, stream>>>(QKVc1, Q1, QKVc2, Q2, DWT);

    // phase 2: fused norms+dots, softmax
    attnA_k<<<dim3(32,16,2), blk, 0, stream>>>(Q1, Q2, PART);
    attnB_k<<<dim3(32), dim3(64), 0, stream>>>(PART, t1, t2, ATT);

    // phase 3+4: attn-out + mid conv + residual -> D16p (both branches)
    mid_k<<<dim3(512,2), blk, 0, stream>>>(Q1, Q2, ATT, x1, x2, W16 + 18432, D16p);

    // phase 5: gated FFN tail per branch
    for (int br = 0; br < 2; br++) {
        gemm_k<96,3,2,0,0,true><<<dim3(4,1024), blk, 0, stream>>>(
            D16p, nullptr, 0, W16 + 24576 + br * 36864, GH, 48, 0,
            nullptr, nullptr, nullptr);
        dwtail_k<<<dim3(3072), blk, 0, stream>>>(
            GH, Xg, DWT + 2592 + br * 192, DWT + (br ? 7776 : 6048));
        if (br == 0)
            gemm_k<96,6,2,0,0,false><<<dim3(1024,1), blk, 0, stream>>>(
                Xg, nullptr, 0, W16 + 98304, ACC, 12, 0, nullptr, nullptr, nullptr);
        else
            gemm_k<96,6,2,0,3,false><<<dim3(1024,1), blk, 0, stream>>>(
                Xg, nullptr, 0, W16 + 116736, nullptr, 0, 0, dout, D16p, ACC);
    }
}

// Round 18
// 382.110 us; speedup vs baseline: 1.0663x; 1.0312x over previous
//
#include <hip/hip_runtime.h>
#include <math.h>

#define HW_ 65536

typedef __attribute__((ext_vector_type(8))) short b16x8;
typedef __attribute__((ext_vector_type(4))) short b16x4;
typedef __attribute__((ext_vector_type(4))) float f32x4;
typedef __attribute__((ext_vector_type(2))) float f32x2;

__device__ __forceinline__ unsigned short f2b(float f) {
    union { float f; unsigned u; } v; v.f = f;
    unsigned r = v.u + 0x7fffu + ((v.u >> 16) & 1u);
    return (unsigned short)(r >> 16);
}
__device__ __forceinline__ float b2f(unsigned short h) {
    union { unsigned u; float f; } v; v.u = ((unsigned)h) << 16; return v.f;
}
__device__ __forceinline__ float gelu_f(float x) {
    float t = 0.7978845608f * fmaf(0.044715f * x, x * x, x);
    float e = __expf(2.f * t);
    float th = 1.f - 2.f / (e + 1.f);
    return 0.5f * x * (1.f + th);
}

// packed dual-fma: v_pk_fma_f32 on CDNA (falls back to scalar if unavailable)
__device__ __forceinline__ f32x2 pk_fma(f32x2 a, f32x2 b, f32x2 c) {
#if __has_builtin(__builtin_elementwise_fma)
    return __builtin_elementwise_fma(a, b, c);
#else
    f32x2 r; r[0] = fmaf(a[0], b[0], c[0]); r[1] = fmaf(a[1], b[1], c[1]);
    return r;
#endif
}

__device__ __forceinline__ float wave_reduce_sum(float v) {
    #pragma unroll
    for (int off = 32; off; off >>= 1) v += __shfl_down(v, off, 64);
    return v;
}

// Blocked bf16 layout: element (px, ch) of a CC*8-channel tensor lives at
//   ((px>>4)*CC + (ch>>3))*128 + (px&15)*8 + (ch&7)
__device__ __forceinline__ size_t baddr(long px, int CC, int g) {
    return (((size_t)(px >> 4)) * CC + g) * 128 + ((size_t)(px & 15) << 3);
}

// ---------------------------------------------------------------------------
// Weight prep (unchanged).
// ---------------------------------------------------------------------------
__global__ __launch_bounds__(256) void wprep_k(
    const float* __restrict__ q1w, const float* __restrict__ q2w,
    const float* __restrict__ m1w, const float* __restrict__ m2w,
    const float* __restrict__ pEw, const float* __restrict__ p1w,
    const float* __restrict__ p2w, const float* __restrict__ o1w,
    const float* __restrict__ o2w,
    const float* __restrict__ q1dw, const float* __restrict__ q2dw,
    const float* __restrict__ pEdw, const float* __restrict__ p1dw,
    const float* __restrict__ p2dw,
    unsigned short* __restrict__ wt, float* __restrict__ dwt)
{
    const int idx = blockIdx.x * 256 + threadIdx.x;
    if (idx < 135168) {
        const int base[8] = {0,9216,18432,21504,24576,61440,98304,116736};
        int s = 0;
        #pragma unroll
        for (int i = 1; i < 8; i++) if (idx >= base[i]) s = i;
        const int local = idx - base[s];
        float v = 0.f;
        if (s < 4) {
            const int m = local >> 6, k = local & 63;
            const float* src = (s == 0) ? q1w : (s == 1) ? q2w : (s == 2) ? m1w : m2w;
            if (k < 48) v = src[m * 48 + k];
        } else if (s < 6) {
            const int br = s - 4;
            const int m = local / 96, k = local % 96;
            if (m < 192) {
                v = pEw[(size_t)(br * 192 + m) * 96 + k];
            } else {
                const float* p12 = br ? p2w : p1w;
                const int lo = br * 48, m2 = m - 192;
                if (k >= lo && k < lo + 48) v = p12[m2 * 48 + (k - lo)];
            }
        } else {
            const int m = local / 192, k = local % 192;
            v = ((s == 6) ? o1w : o2w)[m * 192 + k];
        }
        wt[idx] = f2b(v);
    } else if (idx < 135168 + 9504) {
        const int d = idx - 135168;
        const int dbase[5] = {0,1296,2592,6048,7776};
        const int Cs[5] = {144,144,384,192,192};
        int s = 0;
        #pragma unroll
        for (int i = 1; i < 5; i++) if (d >= dbase[i]) s = i;
        const int local = d - dbase[s], C = Cs[s];
        const int t = local / C, c = local % C;
        const float* src = (s == 0) ? q1dw : (s == 1) ? q2dw : (s == 2) ? pEdw
                         : (s == 3) ? p1dw : p2dw;
        dwt[d] = src[c * 9 + t];
    }
}

// ---------------------------------------------------------------------------
// MFMA GEMM.
// GRIDMODE 0: pxblk = blockIdx.x, mb = blockIdx.y. blockIdx.z may select a
//   second (Bf32b, W16b, out16b) problem (used to merge the two qkv convs).
// GRIDMODE 2: flat XCD-banded grid (4096 blocks, 4 m-blocks): each XCD gets a
//   contiguous px-tile range with ALL m-blocks -> D16p tile fetched once/XCD.
// EPI 0: blocked bf16 store. EPI 1: dout = res + acc. EPI 2: dout += acc.
// EPI 3: dout = b2f(res) + b2f(acc16) + acc.
// ---------------------------------------------------------------------------
template<int BM, int KC, int NT, int BSRC, int EPI, int GRIDMODE>
__global__ __launch_bounds__(256) void gemm_k(
    const unsigned short* __restrict__ B16,
    const float* __restrict__ Bf32, int Cin,
    const unsigned short* __restrict__ W16,
    unsigned short* __restrict__ out16, int CCo, int Coff,
    float* __restrict__ outf, const unsigned short* __restrict__ res,
    const unsigned short* __restrict__ acc16,
    const float* __restrict__ Bf32b, const unsigned short* __restrict__ W16b,
    unsigned short* __restrict__ out16b)
{
    constexpr int MF = BM / 16;
    const int tid = threadIdx.x;
    const int lane = tid & 63, w = tid >> 6;
    const int lm = lane & 15, lk = lane >> 4;

    int mb, pxblk;
    if (GRIDMODE == 2) {
        const int bx = blockIdx.x;                  // 4096 blocks
        const int sb = (bx & 7) * 512 + (bx >> 3);  // XCD-contiguous
        mb = sb & 3; pxblk = sb >> 2;
    } else {
        mb = blockIdx.y; pxblk = blockIdx.x;
    }

    const float* Bf = Bf32;
    const unsigned short* Wp = W16;
    unsigned short* outp = out16;
    if (GRIDMODE == 0 && BSRC == 1 && blockIdx.z) {
        Bf = Bf32b; Wp = W16b; outp = out16b;
    }

    const int m0 = mb * BM;
    const long wavepx = ((long)pxblk * 4 + w) * (NT * 16);
    const long pxb0 = wavepx >> 4;

    f32x4 acc[NT][MF];
    #pragma unroll
    for (int nt = 0; nt < NT; nt++)
        #pragma unroll
        for (int m = 0; m < MF; m++)
            #pragma unroll
            for (int j = 0; j < 4; j++) acc[nt][m][j] = 0.f;

    #pragma unroll
    for (int kc = 0; kc < KC; kc++) {
        b16x8 a[MF];
        #pragma unroll
        for (int m = 0; m < MF; m++)
            a[m] = *(const b16x8*)&Wp[(size_t)(m0 + m * 16 + lm) * (KC * 32) + kc * 32 + lk * 8];
        #pragma unroll
        for (int nt = 0; nt < NT; nt++) {
            b16x8 bb;
            if (BSRC == 0) {
                bb = *(const b16x8*)&B16[((pxb0 + nt) * (KC * 4) + (kc * 4 + lk)) * 128 + lm * 8];
            } else {
                const long px = wavepx + nt * 16 + lm;
                const int p = (int)(px & 65535), bat = (int)(px >> 16);
                #pragma unroll
                for (int j = 0; j < 8; j++) {
                    const int c = kc * 32 + lk * 8 + j;
                    float v = (c < Cin) ? Bf[((size_t)(bat * Cin + c) << 16) + p] : 0.f;
                    bb[j] = (short)f2b(v);
                }
            }
            #pragma unroll
            for (int m = 0; m < MF; m++)
                acc[nt][m] = __builtin_amdgcn_mfma_f32_16x16x32_bf16(a[m], bb, acc[nt][m], 0, 0, 0);
        }
    }

    #pragma unroll
    for (int nt = 0; nt < NT; nt++) {
        const long px = wavepx + nt * 16 + lm;
        #pragma unroll
        for (int m = 0; m < MF; m++) {
            const int mrow = m * 16 + lk * 4;
            if (EPI == 0) {
                b16x4 o;
                #pragma unroll
                for (int j = 0; j < 4; j++) o[j] = (short)f2b(acc[nt][m][j]);
                const int ch = Coff + m0 + mrow;
                *(b16x4*)&outp[((pxb0 + nt) * CCo + (ch >> 3)) * 128 + lm * 8 + (ch & 7)] = o;
            } else if (EPI == 1) {
                const int p = (int)(px & 65535), bat = (int)(px >> 16);
                b16x4 r4 = *(const b16x4*)&res[((pxb0 + nt) * 12 + (mrow >> 3)) * 128 + lm * 8 + (mrow & 7)];
                #pragma unroll
                for (int j = 0; j < 4; j++)
                    outf[((size_t)(bat * 96 + mrow + j) << 16) + p]
                        = acc[nt][m][j] + b2f((unsigned short)r4[j]);
            } else if (EPI == 2) {
                const int p = (int)(px & 65535), bat = (int)(px >> 16);
                #pragma unroll
                for (int j = 0; j < 4; j++) {
                    const size_t adr = ((size_t)(bat * 96 + mrow + j) << 16) + p;
                    outf[adr] += acc[nt][m][j];
                }
            } else {
                const int p = (int)(px & 65535), bat = (int)(px >> 16);
                const size_t boffi = ((pxb0 + nt) * 12 + (mrow >> 3)) * 128 + lm * 8 + (mrow & 7);
                b16x4 r4 = *(const b16x4*)&res[boffi];
                b16x4 a4 = *(const b16x4*)&acc16[boffi];
                #pragma unroll
                for (int j = 0; j < 4; j++)
                    outf[((size_t)(bat * 96 + mrow + j) << 16) + p]
                        = acc[nt][m][j] + b2f((unsigned short)r4[j]) + b2f((unsigned short)a4[j]);
            }
        }
    }
}

// ---------------------------------------------------------------------------
// Packed unpack: uint4 (8 bf16) -> 4 x f32x2.
// ---------------------------------------------------------------------------
__device__ __forceinline__ void unpack8v(const uint4 u, f32x2 f[4]) {
    union { unsigned u; float f; } a, b;
    a.u = u.x << 16; b.u = u.x & 0xFFFF0000u; f[0][0] = a.f; f[0][1] = b.f;
    a.u = u.y << 16; b.u = u.y & 0xFFFF0000u; f[1][0] = a.f; f[1][1] = b.f;
    a.u = u.z << 16; b.u = u.z & 0xFFFF0000u; f[2][0] = a.f; f[2][1] = b.f;
    a.u = u.w << 16; b.u = u.w & 0xFFFF0000u; f[3][0] = a.f; f[3][1] = b.f;
}

// ---------------------------------------------------------------------------
// dw 4px row core, static addressing + packed f32x2 FMAs (v_pk_fma_f32).
// ---------------------------------------------------------------------------
__device__ __forceinline__ void dw_row4(
    f32x2 acc[4][4], const unsigned short* __restrict__ T,
    size_t cb, long lOff, long rOff, bool lval, bool rval,
    const float* __restrict__ wrow, int wstr)
{
    f32x2 w[3][4];
    #pragma unroll
    for (int tx = 0; tx < 3; tx++) {
        const float4 a = *(const float4*)(wrow + (size_t)tx * wstr);
        const float4 b = *(const float4*)(wrow + (size_t)tx * wstr + 4);
        w[tx][0][0] = a.x; w[tx][0][1] = a.y;
        w[tx][1][0] = a.z; w[tx][1][1] = a.w;
        w[tx][2][0] = b.x; w[tx][2][1] = b.y;
        w[tx][3][0] = b.z; w[tx][3][1] = b.w;
    }
    uint4 u[6];
    if (lval) u[0] = *(const uint4*)&T[cb + lOff];
    else      u[0] = make_uint4(0u, 0u, 0u, 0u);
    #pragma unroll
    for (int c = 0; c < 4; c++) u[c + 1] = *(const uint4*)&T[cb + (size_t)c * 8];
    if (rval) u[5] = *(const uint4*)&T[cb + rOff];
    else      u[5] = make_uint4(0u, 0u, 0u, 0u);

    #pragma unroll
    for (int d = 0; d < 6; d++) {
        f32x2 f[4];
        unpack8v(u[d], f);
        #pragma unroll
        for (int tx = 0; tx < 3; tx++) {
            const int p = d - tx;
            if (p >= 0 && p < 4)
                #pragma unroll
                for (int q = 0; q < 4; q++)
                    acc[p][q] = pk_fma(w[tx][q], f[q], acc[p][q]);
        }
    }
}

// phase-1 depthwise: 144 ch (18 chunks), both branches via blockIdx.z.
__global__ __launch_bounds__(256) void dw144_k(
    const unsigned short* __restrict__ in1, unsigned short* __restrict__ out1,
    const unsigned short* __restrict__ in2, unsigned short* __restrict__ out2,
    const float* __restrict__ dwt)
{
    const int z = blockIdx.z;
    const unsigned short* in = z ? in2 : in1;
    unsigned short* out = z ? out2 : out1;
    const float* wt = dwt + z * 1296;
    const int bx = blockIdx.x;
    const int sb = (bx & 7) * 288 + (bx >> 3);
    const int idx = sb * 256 + threadIdx.x;   // < 589824
    const int pbi = idx / 72;
    const int rem = idx - pbi * 72;
    const int g = rem >> 2, i = rem & 3;
    const long px0 = (long)pbi * 16 + i * 4;
    const int x0 = (int)(px0 & 255);
    const int y = (int)((px0 >> 8) & 255);
    const bool lval = x0 > 0, rval = x0 < 252;
    const int off = (int)(px0 & 15) * 8;
    const size_t cb0 = ((size_t)(px0 >> 4) * 18 + g) * 128 + off;
    const long lOff = (off == 0) ? (120 - 18 * 128) : -8;
    const long rOff = (off == 96) ? (18 * 128 - 96) : 32;
    const long dyStep = 16 * 18 * 128;

    f32x2 acc[4][4];
    #pragma unroll
    for (int p = 0; p < 4; p++)
        #pragma unroll
        for (int q = 0; q < 4; q++) { acc[p][q][0] = 0.f; acc[p][q][1] = 0.f; }

    #pragma unroll
    for (int dy = -1; dy <= 1; dy++) {
        const int yy = y + dy;
        if ((unsigned)yy >= 256u) continue;
        const size_t cb = cb0 + (size_t)((long)dy * dyStep);
        dw_row4(acc, in, cb, lOff, rOff, lval, rval,
                wt + g * 8 + (size_t)(dy + 1) * 3 * 144, 144);
    }

    #pragma unroll
    for (int p = 0; p < 4; p++) {
        b16x8 o;
        #pragma unroll
        for (int j = 0; j < 8; j++) o[j] = (short)f2b(acc[p][j >> 1][j & 1]);
        *(b16x8*)&out[cb0 + (size_t)p * 8] = o;
    }
}

// tail fused: Xg = gelu(dw(GH ch 0..191)) * dw(GH ch 192..383). blocked.
// 4px x 8ch, default launch bounds, packed FMAs (r17 proven, 60 us).
__global__ __launch_bounds__(256) void dwtail_k(
    const unsigned short* __restrict__ GH, unsigned short* __restrict__ Xg,
    const float* __restrict__ dwtG, const float* __restrict__ dwtH)
{
    const int bx = blockIdx.x;
    const int sb = (bx & 7) * 384 + (bx >> 3);
    const int idx = sb * 256 + threadIdx.x;   // < 786432
    const int pbi = idx / 96;
    const int rem = idx - pbi * 96;
    const int g = rem >> 2, i = rem & 3;
    const long px0 = (long)pbi * 16 + i * 4;
    const int x0 = (int)(px0 & 255);
    const int y = (int)((px0 >> 8) & 255);
    const bool lval = x0 > 0, rval = x0 < 252;
    const int off = (int)(px0 & 15) * 8;
    const size_t cb0 = ((size_t)(px0 >> 4) * 48 + g) * 128 + off;   // G base
    const long lOff = (off == 0) ? (120 - 48 * 128) : -8;
    const long rOff = (off == 96) ? (48 * 128 - 96) : 32;
    const long dyStep = 16 * 48 * 128;

    f32x2 aG[4][4], aH[4][4];
    #pragma unroll
    for (int p = 0; p < 4; p++)
        #pragma unroll
        for (int q = 0; q < 4; q++) {
            aG[p][q][0] = 0.f; aG[p][q][1] = 0.f;
            aH[p][q][0] = 0.f; aH[p][q][1] = 0.f;
        }

    #pragma unroll
    for (int dy = -1; dy <= 1; dy++) {
        const int yy = y + dy;
        if ((unsigned)yy >= 256u) continue;
        const size_t cb = cb0 + (size_t)((long)dy * dyStep);
        dw_row4(aG, GH, cb, lOff, rOff, lval, rval,
                dwtG + g * 8 + (size_t)(dy + 1) * 3 * 384, 384);
        dw_row4(aH, GH, cb + 3072, lOff, rOff, lval, rval,
                dwtH + g * 8 + (size_t)(dy + 1) * 3 * 192, 192);
    }

    const size_t ob = ((size_t)(px0 >> 4) * 24 + g) * 128 + off;
    #pragma unroll
    for (int p = 0; p < 4; p++) {
        b16x8 o;
        #pragma unroll
        for (int j = 0; j < 8; j++)
            o[j] = (short)f2b(gelu_f(aG[p][j >> 1][j & 1]) * aH[p][j >> 1][j & 1]);
        *(b16x8*)&Xg[ob + (size_t)p * 8] = o;
    }
}

// ---------------------------------------------------------------------------
// Attention stage A (unchanged).
// ---------------------------------------------------------------------------
__global__ __launch_bounds__(256) void attnA_k(
    const unsigned short* __restrict__ Q1, const unsigned short* __restrict__ Q2,
    float* __restrict__ part)
{
    const int tid = threadIdx.x;
    const int chunk = blockIdx.x, bh = blockIdx.y, a = blockIdx.z;
    const int b = bh >> 3, h = bh & 7;
    const unsigned* Qq = (const unsigned*)(a ? Q1 : Q2);
    const unsigned* Qk = (const unsigned*)(a ? Q2 : Q1);
    const int u0 = h * 3;
    const int cq = u0 >> 2, o = u0 & 3;
    const int ck = (24 + u0) >> 2;

    float dot[36], nq[6], nk[6];
    #pragma unroll
    for (int i = 0; i < 36; i++) dot[i] = 0.f;
    #pragma unroll
    for (int i = 0; i < 6; i++) { nq[i] = 0.f; nk[i] = 0.f; }

    #pragma unroll 1
    for (int r = 0; r < 8; r++) {
        const long px = (long)b * 65536 + chunk * 2048 + r * 256 + tid;
        const size_t rowu = ((size_t)(px >> 4)) * 18 * 64 + ((px & 15) << 2);
        const uint4 qa = *(const uint4*)&Qq[rowu + (size_t)cq * 64];
        const uint4 qb = *(const uint4*)&Qq[rowu + (size_t)(cq + 1) * 64];
        const uint4 ka = *(const uint4*)&Qk[rowu + (size_t)ck * 64];
        const uint4 kb = *(const uint4*)&Qk[rowu + (size_t)(ck + 1) * 64];
        unsigned uq[3], uk[3];
        if (o == 0)      { uq[0]=qa.x; uq[1]=qa.y; uq[2]=qa.z; uk[0]=ka.x; uk[1]=ka.y; uk[2]=ka.z; }
        else if (o == 1) { uq[0]=qa.y; uq[1]=qa.z; uq[2]=qa.w; uk[0]=ka.y; uk[1]=ka.z; uk[2]=ka.w; }
        else if (o == 2) { uq[0]=qa.z; uq[1]=qa.w; uq[2]=qb.x; uk[0]=ka.z; uk[1]=ka.w; uk[2]=kb.x; }
        else             { uq[0]=qa.w; uq[1]=qb.x; uq[2]=qb.y; uk[0]=ka.w; uk[1]=kb.x; uk[2]=kb.y; }
        float q[6], k[6];
        #pragma unroll
        for (int i = 0; i < 3; i++) {
            union { unsigned u; float f; } lo, hi;
            lo.u = uq[i] << 16; hi.u = uq[i] & 0xFFFF0000u;
            q[2 * i] = lo.f; q[2 * i + 1] = hi.f;
            lo.u = uk[i] << 16; hi.u = uk[i] & 0xFFFF0000u;
            k[2 * i] = lo.f; k[2 * i + 1] = hi.f;
        }
        #pragma unroll
        for (int c = 0; c < 6; c++) nq[c] = fmaf(q[c], q[c], nq[c]);
        #pragma unroll
        for (int d = 0; d < 6; d++) nk[d] = fmaf(k[d], k[d], nk[d]);
        #pragma unroll
        for (int c = 0; c < 6; c++)
            #pragma unroll
            for (int d = 0; d < 6; d++) dot[c * 6 + d] = fmaf(q[c], k[d], dot[c * 6 + d]);
    }

    __shared__ float red[4][48];
    const int lane = tid & 63, wid = tid >> 6;
    #pragma unroll
    for (int i = 0; i < 48; i++) {
        float v = (i < 36) ? dot[i] : (i < 42 ? nq[i - 36] : nk[i - 42]);
        v = wave_reduce_sum(v);
        if (!lane) red[wid][i] = v;
    }
    __syncthreads();
    if (tid < 48)
        part[((size_t)((a * 16 + bh) * 32 + chunk)) * 48 + tid]
            = red[0][tid] + red[1][tid] + red[2][tid] + red[3][tid];
}

__global__ void attnB_k(const float* __restrict__ part,
                        const float* __restrict__ t1, const float* __restrict__ t2,
                        float* __restrict__ att)
{
    const int abh = blockIdx.x, tid = threadIdx.x;
    const int a = abh >> 4, b = (abh >> 3) & 1, h = abh & 7;
    __shared__ float s[48];
    if (tid < 48) {
        float v = 0.f;
        for (int ch = 0; ch < 32; ch++) v += part[((size_t)abh * 32 + ch) * 48 + tid];
        s[tid] = v;
    }
    __syncthreads();
    if (tid < 6) {
        const int c = tid;
        const float tv = a ? t2[h] : t1[h];
        const float qn = fmaxf(sqrtf(s[36 + c]), 1e-12f);
        float raw[6];
        #pragma unroll
        for (int d = 0; d < 6; d++)
            raw[d] = tv * s[c * 6 + d] / (qn * fmaxf(sqrtf(s[42 + d]), 1e-12f));
        float m = raw[0];
        #pragma unroll
        for (int d = 1; d < 6; d++) m = fmaxf(m, raw[d]);
        float e[6], sum = 0.f;
        #pragma unroll
        for (int d = 0; d < 6; d++) { e[d] = expf(raw[d] - m); sum += e[d]; }
        const float inv = 1.f / sum;
        #pragma unroll
        for (int d = 0; d < 6; d++)
            att[((size_t)(a * 2 + b) * 8 + h) * 36 + c * 6 + d] = e[d] * inv;
    }
}

// ---------------------------------------------------------------------------
// Fused attn-out + mid conv + residual (unchanged).
// ---------------------------------------------------------------------------
__global__ __launch_bounds__(256) void mid_k(
    const unsigned short* __restrict__ Q1, const unsigned short* __restrict__ Q2,
    const float* __restrict__ att,
    const float* __restrict__ x1, const float* __restrict__ x2,
    const unsigned short* __restrict__ Wm, unsigned short* __restrict__ D16p)
{
    const int br = blockIdx.y;
    const unsigned short* Qv = br ? Q2 : Q1;
    const float* x = br ? x2 : x1;
    const unsigned short* W16 = Wm + br * 3072;
    const float* attb = att + br * 576;
    const int boff = br * 48;

    __shared__ float atts[288];
    __shared__ unsigned short S[256][72];
    const int tid = threadIdx.x;
    const long px = (long)blockIdx.x * 256 + tid;
    const int bat = (int)(px >> 16);

    for (int i = tid; i < 288; i += 256) atts[i] = attb[bat * 288 + i];

    float v[48];
    #pragma unroll
    for (int i = 0; i < 6; i++) {
        b16x8 t = *(const b16x8*)&Qv[baddr(px, 18, 12 + i)];
        #pragma unroll
        for (int j = 0; j < 8; j++) v[i * 8 + j] = b2f((unsigned short)t[j]);
    }
    __syncthreads();

    #pragma unroll
    for (int h = 0; h < 8; h++) {
        unsigned short sh[6];
        #pragma unroll
        for (int c = 0; c < 6; c++) {
            float s = 0.f;
            #pragma unroll
            for (int d = 0; d < 6; d++) s = fmaf(atts[h * 36 + c * 6 + d], v[h * 6 + d], s);
            sh[c] = f2b(s);
        }
        #pragma unroll
        for (int i = 0; i < 3; i++) {
            unsigned packed = (unsigned)sh[2 * i] | ((unsigned)sh[2 * i + 1] << 16);
            *(unsigned*)&S[tid][h * 6 + 2 * i] = packed;
        }
    }
    #pragma unroll
    for (int i = 0; i < 8; i++) *(unsigned*)&S[tid][48 + 2 * i] = 0u;
    __syncthreads();

    const int lane = tid & 63, w = tid >> 6;
    const int lm = lane & 15, lk = lane >> 4;
    f32x4 acc[4][3];
    #pragma unroll
    for (int nt = 0; nt < 4; nt++)
        #pragma unroll
        for (int m = 0; m < 3; m++)
            #pragma unroll
            for (int j = 0; j < 4; j++) acc[nt][m][j] = 0.f;

    #pragma unroll
    for (int kc = 0; kc < 2; kc++) {
        b16x8 a[3];
        #pragma unroll
        for (int m = 0; m < 3; m++)
            a[m] = *(const b16x8*)&W16[(size_t)(m * 16 + lm) * 64 + kc * 32 + lk * 8];
        #pragma unroll
        for (int nt = 0; nt < 4; nt++) {
            b16x8 bb = *(const b16x8*)&S[w * 64 + nt * 16 + lm][kc * 32 + lk * 8];
            #pragma unroll
            for (int m = 0; m < 3; m++)
                acc[nt][m] = __builtin_amdgcn_mfma_f32_16x16x32_bf16(a[m], bb, acc[nt][m], 0, 0, 0);
        }
    }

    #pragma unroll
    for (int nt = 0; nt < 4; nt++) {
        const long px2 = (long)blockIdx.x * 256 + w * 64 + nt * 16 + lm;
        const int p2 = (int)(px2 & 65535);
        const long pxb2 = px2 >> 4;
        #pragma unroll
        for (int m = 0; m < 3; m++) {
            const int row = m * 16 + lk * 4;
            b16x4 o;
            #pragma unroll
            for (int j = 0; j < 4; j++) {
                float xv = x[((size_t)(bat * 48 + row + j) << 16) + p2];
                o[j] = (short)f2b(acc[nt][m][j] + xv);
            }
            const int ch = boff + row;
            *(b16x4*)&D16p[(pxb2 * 12 + (ch >> 3)) * 128 + lm * 8 + (ch & 7)] = o;
        }
    }
}

extern "C" void kernel_launch(void* const* d_in, const int* in_sizes, int n_in,
                              void* d_out, int out_size, void* d_ws, size_t ws_size,
                              hipStream_t stream) {
    const float* x1      = (const float*)d_in[0];
    const float* x2      = (const float*)d_in[1];
    const float* t1      = (const float*)d_in[2];
    const float* t2      = (const float*)d_in[3];
    const float* qkv1_w  = (const float*)d_in[4];
    const float* qkv1_dw = (const float*)d_in[5];
    const float* qkv2_w  = (const float*)d_in[6];
    const float* qkv2_dw = (const float*)d_in[7];
    const float* mid1_w  = (const float*)d_in[8];
    const float* mid2_w  = (const float*)d_in[9];
    const float* pE_w    = (const float*)d_in[10];
    const float* pE_dw   = (const float*)d_in[11];
    const float* pE1_w   = (const float*)d_in[12];
    const float* pE1_dw  = (const float*)d_in[13];
    const float* pE2_w   = (const float*)d_in[14];
    const float* pE2_dw  = (const float*)d_in[15];
    const float* po1_w   = (const float*)d_in[16];
    const float* po2_w   = (const float*)d_in[17];
    float* dout = (float*)d_out;
    char* ws = (char*)d_ws;

    // workspace layout (bytes); peak ~201.8 MB
    unsigned short* D16p  = (unsigned short*)(ws + 0);
    unsigned short* QKVc1 = (unsigned short*)(ws + 25165824);
    unsigned short* QKVc2 = (unsigned short*)(ws + 62914560);
    unsigned short* Q1    = (unsigned short*)(ws + 100663296);
    unsigned short* Q2    = (unsigned short*)(ws + 138412032);
    unsigned short* GH    = (unsigned short*)(ws + 25165824);     // phase5 overlay
    unsigned short* Xg    = (unsigned short*)(ws + 125829120);    // phase5 overlay
    float*          PART  = (float*)(ws + 176160768);
    float*          ATT   = (float*)(ws + 176357376);
    unsigned short* W16   = (unsigned short*)(ws + 176361984);
    float*          DWT   = (float*)(ws + 176632320);             // ends 176,670,336
    unsigned short* ACC   = (unsigned short*)(ws + 176670720);    // 25,165,824 B

    const dim3 blk(256);

    wprep_k<<<dim3(566), blk, 0, stream>>>(
        qkv1_w, qkv2_w, mid1_w, mid2_w, pE_w, pE1_w, pE2_w, po1_w, po2_w,
        qkv1_dw, qkv2_dw, pE_dw, pE1_dw, pE2_dw, W16, DWT);

    // phase 1: qkv conv (fp32 NCHW input), both branches in one launch
    gemm_k<144,2,2,1,0,0><<<dim3(1024,1,2), blk, 0, stream>>>(
        nullptr, x1, 48, W16, QKVc1, 18, 0, nullptr, nullptr, nullptr,
        x2, W16 + 9216, QKVc2);
    dw144_k<<<dim3(2304,1,2), blk, 0, stream>>>(QKVc1, Q1, QKVc2, Q2, DWT);

    // phase 2: fused norms+dots, softmax
    attnA_k<<<dim3(32,16,2), blk, 0, stream>>>(Q1, Q2, PART);
    attnB_k<<<dim3(32), dim3(64), 0, stream>>>(PART, t1, t2, ATT);

    // phase 3+4: attn-out + mid conv + residual -> D16p (both branches)
    mid_k<<<dim3(512,2), blk, 0, stream>>>(Q1, Q2, ATT, x1, x2, W16 + 18432, D16p);

    // phase 5: gated FFN tail per branch
    for (int br = 0; br < 2; br++) {
        // GH gemm: XCD-banded flat grid so all 4 m-blocks of one px-tile land
        // on the same XCD -> D16p tile fetched once per XCD L2.
        gemm_k<96,3,2,0,0,2><<<dim3(4096), blk, 0, stream>>>(
            D16p, nullptr, 0, W16 + 24576 + br * 36864, GH, 48, 0,
            nullptr, nullptr, nullptr, nullptr, nullptr, nullptr);
        dwtail_k<<<dim3(3072), blk, 0, stream>>>(
            GH, Xg, DWT + 2592 + br * 192, DWT + (br ? 7776 : 6048));
        if (br == 0)
            gemm_k<96,6,2,0,0,0><<<dim3(1024,1), blk, 0, stream>>>(
                Xg, nullptr, 0, W16 + 98304, ACC, 12, 0, nullptr, nullptr, nullptr,
                nullptr, nullptr, nullptr);
        else
            gemm_k<96,6,2,0,3,0><<<dim3(1024,1), blk, 0, stream>>>(
                Xg, nullptr, 0, W16 + 116736, nullptr, 0, 0, dout, D16p, ACC,
                nullptr, nullptr, nullptr);
    }
}

// Round 19
// 377.978 us; speedup vs baseline: 1.0779x; 1.0109x over previous
//
#include <hip/hip_runtime.h>
#include <math.h>

#define HW_ 65536

typedef __attribute__((ext_vector_type(8))) short b16x8;
typedef __attribute__((ext_vector_type(4))) short b16x4;
typedef __attribute__((ext_vector_type(4))) float f32x4;
typedef __attribute__((ext_vector_type(2))) float f32x2;

__device__ __forceinline__ unsigned short f2b(float f) {
    union { float f; unsigned u; } v; v.f = f;
    unsigned r = v.u + 0x7fffu + ((v.u >> 16) & 1u);
    return (unsigned short)(r >> 16);
}
__device__ __forceinline__ float b2f(unsigned short h) {
    union { unsigned u; float f; } v; v.u = ((unsigned)h) << 16; return v.f;
}
__device__ __forceinline__ float gelu_f(float x) {
    float t = 0.7978845608f * fmaf(0.044715f * x, x * x, x);
    float e = __expf(2.f * t);
    float th = 1.f - 2.f / (e + 1.f);
    return 0.5f * x * (1.f + th);
}

// packed dual-fma: v_pk_fma_f32 on CDNA (falls back to scalar if unavailable)
__device__ __forceinline__ f32x2 pk_fma(f32x2 a, f32x2 b, f32x2 c) {
#if __has_builtin(__builtin_elementwise_fma)
    return __builtin_elementwise_fma(a, b, c);
#else
    f32x2 r; r[0] = fmaf(a[0], b[0], c[0]); r[1] = fmaf(a[1], b[1], c[1]);
    return r;
#endif
}

__device__ __forceinline__ float wave_reduce_sum(float v) {
    #pragma unroll
    for (int off = 32; off; off >>= 1) v += __shfl_down(v, off, 64);
    return v;
}

// Blocked bf16 layout: element (px, ch) of a CC*8-channel tensor lives at
//   ((px>>4)*CC + (ch>>3))*128 + (px&15)*8 + (ch&7)
__device__ __forceinline__ size_t baddr(long px, int CC, int g) {
    return (((size_t)(px >> 4)) * CC + g) * 128 + ((size_t)(px & 15) << 3);
}

// ---------------------------------------------------------------------------
// Weight prep (unchanged).
// ---------------------------------------------------------------------------
__global__ __launch_bounds__(256) void wprep_k(
    const float* __restrict__ q1w, const float* __restrict__ q2w,
    const float* __restrict__ m1w, const float* __restrict__ m2w,
    const float* __restrict__ pEw, const float* __restrict__ p1w,
    const float* __restrict__ p2w, const float* __restrict__ o1w,
    const float* __restrict__ o2w,
    const float* __restrict__ q1dw, const float* __restrict__ q2dw,
    const float* __restrict__ pEdw, const float* __restrict__ p1dw,
    const float* __restrict__ p2dw,
    unsigned short* __restrict__ wt, float* __restrict__ dwt)
{
    const int idx = blockIdx.x * 256 + threadIdx.x;
    if (idx < 135168) {
        const int base[8] = {0,9216,18432,21504,24576,61440,98304,116736};
        int s = 0;
        #pragma unroll
        for (int i = 1; i < 8; i++) if (idx >= base[i]) s = i;
        const int local = idx - base[s];
        float v = 0.f;
        if (s < 4) {
            const int m = local >> 6, k = local & 63;
            const float* src = (s == 0) ? q1w : (s == 1) ? q2w : (s == 2) ? m1w : m2w;
            if (k < 48) v = src[m * 48 + k];
        } else if (s < 6) {
            const int br = s - 4;
            const int m = local / 96, k = local % 96;
            if (m < 192) {
                v = pEw[(size_t)(br * 192 + m) * 96 + k];
            } else {
                const float* p12 = br ? p2w : p1w;
                const int lo = br * 48, m2 = m - 192;
                if (k >= lo && k < lo + 48) v = p12[m2 * 48 + (k - lo)];
            }
        } else {
            const int m = local / 192, k = local % 192;
            v = ((s == 6) ? o1w : o2w)[m * 192 + k];
        }
        wt[idx] = f2b(v);
    } else if (idx < 135168 + 9504) {
        const int d = idx - 135168;
        const int dbase[5] = {0,1296,2592,6048,7776};
        const int Cs[5] = {144,144,384,192,192};
        int s = 0;
        #pragma unroll
        for (int i = 1; i < 5; i++) if (d >= dbase[i]) s = i;
        const int local = d - dbase[s], C = Cs[s];
        const int t = local / C, c = local % C;
        const float* src = (s == 0) ? q1dw : (s == 1) ? q2dw : (s == 2) ? pEdw
                         : (s == 3) ? p1dw : p2dw;
        dwt[d] = src[c * 9 + t];
    }
}

// ---------------------------------------------------------------------------
// MFMA GEMM (unchanged from r18).
// ---------------------------------------------------------------------------
template<int BM, int KC, int NT, int BSRC, int EPI, int GRIDMODE>
__global__ __launch_bounds__(256) void gemm_k(
    const unsigned short* __restrict__ B16,
    const float* __restrict__ Bf32, int Cin,
    const unsigned short* __restrict__ W16,
    unsigned short* __restrict__ out16, int CCo, int Coff,
    float* __restrict__ outf, const unsigned short* __restrict__ res,
    const unsigned short* __restrict__ acc16,
    const float* __restrict__ Bf32b, const unsigned short* __restrict__ W16b,
    unsigned short* __restrict__ out16b)
{
    constexpr int MF = BM / 16;
    const int tid = threadIdx.x;
    const int lane = tid & 63, w = tid >> 6;
    const int lm = lane & 15, lk = lane >> 4;

    int mb, pxblk;
    if (GRIDMODE == 2) {
        const int bx = blockIdx.x;                  // 4096 blocks
        const int sb = (bx & 7) * 512 + (bx >> 3);  // XCD-contiguous
        mb = sb & 3; pxblk = sb >> 2;
    } else {
        mb = blockIdx.y; pxblk = blockIdx.x;
    }

    const float* Bf = Bf32;
    const unsigned short* Wp = W16;
    unsigned short* outp = out16;
    if (GRIDMODE == 0 && BSRC == 1 && blockIdx.z) {
        Bf = Bf32b; Wp = W16b; outp = out16b;
    }

    const int m0 = mb * BM;
    const long wavepx = ((long)pxblk * 4 + w) * (NT * 16);
    const long pxb0 = wavepx >> 4;

    f32x4 acc[NT][MF];
    #pragma unroll
    for (int nt = 0; nt < NT; nt++)
        #pragma unroll
        for (int m = 0; m < MF; m++)
            #pragma unroll
            for (int j = 0; j < 4; j++) acc[nt][m][j] = 0.f;

    #pragma unroll
    for (int kc = 0; kc < KC; kc++) {
        b16x8 a[MF];
        #pragma unroll
        for (int m = 0; m < MF; m++)
            a[m] = *(const b16x8*)&Wp[(size_t)(m0 + m * 16 + lm) * (KC * 32) + kc * 32 + lk * 8];
        #pragma unroll
        for (int nt = 0; nt < NT; nt++) {
            b16x8 bb;
            if (BSRC == 0) {
                bb = *(const b16x8*)&B16[((pxb0 + nt) * (KC * 4) + (kc * 4 + lk)) * 128 + lm * 8];
            } else {
                const long px = wavepx + nt * 16 + lm;
                const int p = (int)(px & 65535), bat = (int)(px >> 16);
                #pragma unroll
                for (int j = 0; j < 8; j++) {
                    const int c = kc * 32 + lk * 8 + j;
                    float v = (c < Cin) ? Bf[((size_t)(bat * Cin + c) << 16) + p] : 0.f;
                    bb[j] = (short)f2b(v);
                }
            }
            #pragma unroll
            for (int m = 0; m < MF; m++)
                acc[nt][m] = __builtin_amdgcn_mfma_f32_16x16x32_bf16(a[m], bb, acc[nt][m], 0, 0, 0);
        }
    }

    #pragma unroll
    for (int nt = 0; nt < NT; nt++) {
        const long px = wavepx + nt * 16 + lm;
        #pragma unroll
        for (int m = 0; m < MF; m++) {
            const int mrow = m * 16 + lk * 4;
            if (EPI == 0) {
                b16x4 o;
                #pragma unroll
                for (int j = 0; j < 4; j++) o[j] = (short)f2b(acc[nt][m][j]);
                const int ch = Coff + m0 + mrow;
                *(b16x4*)&outp[((pxb0 + nt) * CCo + (ch >> 3)) * 128 + lm * 8 + (ch & 7)] = o;
            } else if (EPI == 1) {
                const int p = (int)(px & 65535), bat = (int)(px >> 16);
                b16x4 r4 = *(const b16x4*)&res[((pxb0 + nt) * 12 + (mrow >> 3)) * 128 + lm * 8 + (mrow & 7)];
                #pragma unroll
                for (int j = 0; j < 4; j++)
                    outf[((size_t)(bat * 96 + mrow + j) << 16) + p]
                        = acc[nt][m][j] + b2f((unsigned short)r4[j]);
            } else if (EPI == 2) {
                const int p = (int)(px & 65535), bat = (int)(px >> 16);
                #pragma unroll
                for (int j = 0; j < 4; j++) {
                    const size_t adr = ((size_t)(bat * 96 + mrow + j) << 16) + p;
                    outf[adr] += acc[nt][m][j];
                }
            } else {
                const int p = (int)(px & 65535), bat = (int)(px >> 16);
                const size_t boffi = ((pxb0 + nt) * 12 + (mrow >> 3)) * 128 + lm * 8 + (mrow & 7);
                b16x4 r4 = *(const b16x4*)&res[boffi];
                b16x4 a4 = *(const b16x4*)&acc16[boffi];
                #pragma unroll
                for (int j = 0; j < 4; j++)
                    outf[((size_t)(bat * 96 + mrow + j) << 16) + p]
                        = acc[nt][m][j] + b2f((unsigned short)r4[j]) + b2f((unsigned short)a4[j]);
            }
        }
    }
}

// ---------------------------------------------------------------------------
// Packed unpack: uint4 (8 bf16) -> 4 x f32x2.
// ---------------------------------------------------------------------------
__device__ __forceinline__ void unpack8v(const uint4 u, f32x2 f[4]) {
    union { unsigned u; float f; } a, b;
    a.u = u.x << 16; b.u = u.x & 0xFFFF0000u; f[0][0] = a.f; f[0][1] = b.f;
    a.u = u.y << 16; b.u = u.y & 0xFFFF0000u; f[1][0] = a.f; f[1][1] = b.f;
    a.u = u.z << 16; b.u = u.z & 0xFFFF0000u; f[2][0] = a.f; f[2][1] = b.f;
    a.u = u.w << 16; b.u = u.w & 0xFFFF0000u; f[3][0] = a.f; f[3][1] = b.f;
}

// ---------------------------------------------------------------------------
// dw 4px row core (dw144, unchanged).
// ---------------------------------------------------------------------------
__device__ __forceinline__ void dw_row4(
    f32x2 acc[4][4], const unsigned short* __restrict__ T,
    size_t cb, long lOff, long rOff, bool lval, bool rval,
    const float* __restrict__ wrow, int wstr)
{
    f32x2 w[3][4];
    #pragma unroll
    for (int tx = 0; tx < 3; tx++) {
        const float4 a = *(const float4*)(wrow + (size_t)tx * wstr);
        const float4 b = *(const float4*)(wrow + (size_t)tx * wstr + 4);
        w[tx][0][0] = a.x; w[tx][0][1] = a.y;
        w[tx][1][0] = a.z; w[tx][1][1] = a.w;
        w[tx][2][0] = b.x; w[tx][2][1] = b.y;
        w[tx][3][0] = b.z; w[tx][3][1] = b.w;
    }
    uint4 u[6];
    if (lval) u[0] = *(const uint4*)&T[cb + lOff];
    else      u[0] = make_uint4(0u, 0u, 0u, 0u);
    #pragma unroll
    for (int c = 0; c < 4; c++) u[c + 1] = *(const uint4*)&T[cb + (size_t)c * 8];
    if (rval) u[5] = *(const uint4*)&T[cb + rOff];
    else      u[5] = make_uint4(0u, 0u, 0u, 0u);

    #pragma unroll
    for (int d = 0; d < 6; d++) {
        f32x2 f[4];
        unpack8v(u[d], f);
        #pragma unroll
        for (int tx = 0; tx < 3; tx++) {
            const int p = d - tx;
            if (p >= 0 && p < 4)
                #pragma unroll
                for (int q = 0; q < 4; q++)
                    acc[p][q] = pk_fma(w[tx][q], f[q], acc[p][q]);
        }
    }
}

// ---------------------------------------------------------------------------
// dw 2px row core for dwtail: 4 cols (1 left halo, 2 center, 1 right halo).
// ---------------------------------------------------------------------------
__device__ __forceinline__ void dw_row2(
    f32x2 acc[2][4], const unsigned short* __restrict__ T,
    size_t cb, long lOff, long rOff, bool lval, bool rval,
    const float* __restrict__ wrow, int wstr)
{
    f32x2 w[3][4];
    #pragma unroll
    for (int tx = 0; tx < 3; tx++) {
        const float4 a = *(const float4*)(wrow + (size_t)tx * wstr);
        const float4 b = *(const float4*)(wrow + (size_t)tx * wstr + 4);
        w[tx][0][0] = a.x; w[tx][0][1] = a.y;
        w[tx][1][0] = a.z; w[tx][1][1] = a.w;
        w[tx][2][0] = b.x; w[tx][2][1] = b.y;
        w[tx][3][0] = b.z; w[tx][3][1] = b.w;
    }
    uint4 u[4];
    if (lval) u[0] = *(const uint4*)&T[cb + lOff];
    else      u[0] = make_uint4(0u, 0u, 0u, 0u);
    u[1] = *(const uint4*)&T[cb];
    u[2] = *(const uint4*)&T[cb + 8];
    if (rval) u[3] = *(const uint4*)&T[cb + rOff];
    else      u[3] = make_uint4(0u, 0u, 0u, 0u);

    #pragma unroll
    for (int c = 0; c < 4; c++) {        // input col = px0 - 1 + c
        f32x2 f[4];
        unpack8v(u[c], f);
        #pragma unroll
        for (int tx = 0; tx < 3; tx++) {
            const int p = c - tx;        // output px using this col at tap tx
            if (p >= 0 && p < 2)
                #pragma unroll
                for (int q = 0; q < 4; q++)
                    acc[p][q] = pk_fma(w[tx][q], f[q], acc[p][q]);
        }
    }
}

// phase-1 depthwise: 144 ch (18 chunks), both branches via blockIdx.z.
__global__ __launch_bounds__(256) void dw144_k(
    const unsigned short* __restrict__ in1, unsigned short* __restrict__ out1,
    const unsigned short* __restrict__ in2, unsigned short* __restrict__ out2,
    const float* __restrict__ dwt)
{
    const int z = blockIdx.z;
    const unsigned short* in = z ? in2 : in1;
    unsigned short* out = z ? out2 : out1;
    const float* wt = dwt + z * 1296;
    const int bx = blockIdx.x;
    const int sb = (bx & 7) * 288 + (bx >> 3);
    const int idx = sb * 256 + threadIdx.x;   // < 589824
    const int pbi = idx / 72;
    const int rem = idx - pbi * 72;
    const int g = rem >> 2, i = rem & 3;
    const long px0 = (long)pbi * 16 + i * 4;
    const int x0 = (int)(px0 & 255);
    const int y = (int)((px0 >> 8) & 255);
    const bool lval = x0 > 0, rval = x0 < 252;
    const int off = (int)(px0 & 15) * 8;
    const size_t cb0 = ((size_t)(px0 >> 4) * 18 + g) * 128 + off;
    const long lOff = (off == 0) ? (120 - 18 * 128) : -8;
    const long rOff = (off == 96) ? (18 * 128 - 96) : 32;
    const long dyStep = 16 * 18 * 128;

    f32x2 acc[4][4];
    #pragma unroll
    for (int p = 0; p < 4; p++)
        #pragma unroll
        for (int q = 0; q < 4; q++) { acc[p][q][0] = 0.f; acc[p][q][1] = 0.f; }

    #pragma unroll
    for (int dy = -1; dy <= 1; dy++) {
        const int yy = y + dy;
        if ((unsigned)yy >= 256u) continue;
        const size_t cb = cb0 + (size_t)((long)dy * dyStep);
        dw_row4(acc, in, cb, lOff, rOff, lval, rval,
                wt + g * 8 + (size_t)(dy + 1) * 3 * 144, 144);
    }

    #pragma unroll
    for (int p = 0; p < 4; p++) {
        b16x8 o;
        #pragma unroll
        for (int j = 0; j < 8; j++) o[j] = (short)f2b(acc[p][j >> 1][j & 1]);
        *(b16x8*)&out[cb0 + (size_t)p * 8] = o;
    }
}

// tail fused: Xg = gelu(dw(GH ch 0..191)) * dw(GH ch 192..383). blocked.
// 2px x 8ch per thread (acc 32 VGPR): registers -> occupancy trade.
// 6144 blocks, XCD y-banded.
__global__ __launch_bounds__(256) void dwtail_k(
    const unsigned short* __restrict__ GH, unsigned short* __restrict__ Xg,
    const float* __restrict__ dwtG, const float* __restrict__ dwtH)
{
    const int bx = blockIdx.x;
    const int sb = (bx & 7) * 768 + (bx >> 3);
    const int idx = sb * 256 + threadIdx.x;   // < 1572864
    const int pbi = idx / 192;
    const int rem = idx - pbi * 192;
    const int g = rem >> 3, i = rem & 7;
    const long px0 = (long)pbi * 16 + i * 2;
    const int x0 = (int)(px0 & 255);
    const int y = (int)((px0 >> 8) & 255);
    const bool lval = x0 > 0, rval = x0 < 254;
    const int off = (int)(px0 & 15) * 8;
    const size_t cb0 = ((size_t)(px0 >> 4) * 48 + g) * 128 + off;   // G base
    const long lOff = (off == 0) ? (120 - 48 * 128) : -8;
    const long rOff = (off == 112) ? (48 * 128 - 112) : 16;
    const long dyStep = 16 * 48 * 128;

    f32x2 aG[2][4], aH[2][4];
    #pragma unroll
    for (int p = 0; p < 2; p++)
        #pragma unroll
        for (int q = 0; q < 4; q++) {
            aG[p][q][0] = 0.f; aG[p][q][1] = 0.f;
            aH[p][q][0] = 0.f; aH[p][q][1] = 0.f;
        }

    #pragma unroll
    for (int dy = -1; dy <= 1; dy++) {
        const int yy = y + dy;
        if ((unsigned)yy >= 256u) continue;
        const size_t cb = cb0 + (size_t)((long)dy * dyStep);
        dw_row2(aG, GH, cb, lOff, rOff, lval, rval,
                dwtG + g * 8 + (size_t)(dy + 1) * 3 * 384, 384);
        dw_row2(aH, GH, cb + 3072, lOff, rOff, lval, rval,
                dwtH + g * 8 + (size_t)(dy + 1) * 3 * 192, 192);
    }

    const size_t ob = ((size_t)(px0 >> 4) * 24 + g) * 128 + off;
    #pragma unroll
    for (int p = 0; p < 2; p++) {
        b16x8 o;
        #pragma unroll
        for (int j = 0; j < 8; j++)
            o[j] = (short)f2b(gelu_f(aG[p][j >> 1][j & 1]) * aH[p][j >> 1][j & 1]);
        *(b16x8*)&Xg[ob + (size_t)p * 8] = o;
    }
}

// ---------------------------------------------------------------------------
// Attention stage A (unchanged).
// ---------------------------------------------------------------------------
__global__ __launch_bounds__(256) void attnA_k(
    const unsigned short* __restrict__ Q1, const unsigned short* __restrict__ Q2,
    float* __restrict__ part)
{
    const int tid = threadIdx.x;
    const int chunk = blockIdx.x, bh = blockIdx.y, a = blockIdx.z;
    const int b = bh >> 3, h = bh & 7;
    const unsigned* Qq = (const unsigned*)(a ? Q1 : Q2);
    const unsigned* Qk = (const unsigned*)(a ? Q2 : Q1);
    const int u0 = h * 3;
    const int cq = u0 >> 2, o = u0 & 3;
    const int ck = (24 + u0) >> 2;

    float dot[36], nq[6], nk[6];
    #pragma unroll
    for (int i = 0; i < 36; i++) dot[i] = 0.f;
    #pragma unroll
    for (int i = 0; i < 6; i++) { nq[i] = 0.f; nk[i] = 0.f; }

    #pragma unroll 1
    for (int r = 0; r < 8; r++) {
        const long px = (long)b * 65536 + chunk * 2048 + r * 256 + tid;
        const size_t rowu = ((size_t)(px >> 4)) * 18 * 64 + ((px & 15) << 2);
        const uint4 qa = *(const uint4*)&Qq[rowu + (size_t)cq * 64];
        const uint4 qb = *(const uint4*)&Qq[rowu + (size_t)(cq + 1) * 64];
        const uint4 ka = *(const uint4*)&Qk[rowu + (size_t)ck * 64];
        const uint4 kb = *(const uint4*)&Qk[rowu + (size_t)(ck + 1) * 64];
        unsigned uq[3], uk[3];
        if (o == 0)      { uq[0]=qa.x; uq[1]=qa.y; uq[2]=qa.z; uk[0]=ka.x; uk[1]=ka.y; uk[2]=ka.z; }
        else if (o == 1) { uq[0]=qa.y; uq[1]=qa.z; uq[2]=qa.w; uk[0]=ka.y; uk[1]=ka.z; uk[2]=ka.w; }
        else if (o == 2) { uq[0]=qa.z; uq[1]=qa.w; uq[2]=qb.x; uk[0]=ka.z; uk[1]=ka.w; uk[2]=kb.x; }
        else             { uq[0]=qa.w; uq[1]=qb.x; uq[2]=qb.y; uk[0]=ka.w; uk[1]=kb.x; uk[2]=kb.y; }
        float q[6], k[6];
        #pragma unroll
        for (int i = 0; i < 3; i++) {
            union { unsigned u; float f; } lo, hi;
            lo.u = uq[i] << 16; hi.u = uq[i] & 0xFFFF0000u;
            q[2 * i] = lo.f; q[2 * i + 1] = hi.f;
            lo.u = uk[i] << 16; hi.u = uk[i] & 0xFFFF0000u;
            k[2 * i] = lo.f; k[2 * i + 1] = hi.f;
        }
        #pragma unroll
        for (int c = 0; c < 6; c++) nq[c] = fmaf(q[c], q[c], nq[c]);
        #pragma unroll
        for (int d = 0; d < 6; d++) nk[d] = fmaf(k[d], k[d], nk[d]);
        #pragma unroll
        for (int c = 0; c < 6; c++)
            #pragma unroll
            for (int d = 0; d < 6; d++) dot[c * 6 + d] = fmaf(q[c], k[d], dot[c * 6 + d]);
    }

    __shared__ float red[4][48];
    const int lane = tid & 63, wid = tid >> 6;
    #pragma unroll
    for (int i = 0; i < 48; i++) {
        float v = (i < 36) ? dot[i] : (i < 42 ? nq[i - 36] : nk[i - 42]);
        v = wave_reduce_sum(v);
        if (!lane) red[wid][i] = v;
    }
    __syncthreads();
    if (tid < 48)
        part[((size_t)((a * 16 + bh) * 32 + chunk)) * 48 + tid]
            = red[0][tid] + red[1][tid] + red[2][tid] + red[3][tid];
}

__global__ void attnB_k(const float* __restrict__ part,
                        const float* __restrict__ t1, const float* __restrict__ t2,
                        float* __restrict__ att)
{
    const int abh = blockIdx.x, tid = threadIdx.x;
    const int a = abh >> 4, b = (abh >> 3) & 1, h = abh & 7;
    __shared__ float s[48];
    if (tid < 48) {
        float v = 0.f;
        for (int ch = 0; ch < 32; ch++) v += part[((size_t)abh * 32 + ch) * 48 + tid];
        s[tid] = v;
    }
    __syncthreads();
    if (tid < 6) {
        const int c = tid;
        const float tv = a ? t2[h] : t1[h];
        const float qn = fmaxf(sqrtf(s[36 + c]), 1e-12f);
        float raw[6];
        #pragma unroll
        for (int d = 0; d < 6; d++)
            raw[d] = tv * s[c * 6 + d] / (qn * fmaxf(sqrtf(s[42 + d]), 1e-12f));
        float m = raw[0];
        #pragma unroll
        for (int d = 1; d < 6; d++) m = fmaxf(m, raw[d]);
        float e[6], sum = 0.f;
        #pragma unroll
        for (int d = 0; d < 6; d++) { e[d] = expf(raw[d] - m); sum += e[d]; }
        const float inv = 1.f / sum;
        #pragma unroll
        for (int d = 0; d < 6; d++)
            att[((size_t)(a * 2 + b) * 8 + h) * 36 + c * 6 + d] = e[d] * inv;
    }
}

// ---------------------------------------------------------------------------
// Fused attn-out + mid conv + residual (unchanged).
// ---------------------------------------------------------------------------
__global__ __launch_bounds__(256) void mid_k(
    const unsigned short* __restrict__ Q1, const unsigned short* __restrict__ Q2,
    const float* __restrict__ att,
    const float* __restrict__ x1, const float* __restrict__ x2,
    const unsigned short* __restrict__ Wm, unsigned short* __restrict__ D16p)
{
    const int br = blockIdx.y;
    const unsigned short* Qv = br ? Q2 : Q1;
    const float* x = br ? x2 : x1;
    const unsigned short* W16 = Wm + br * 3072;
    const float* attb = att + br * 576;
    const int boff = br * 48;

    __shared__ float atts[288];
    __shared__ unsigned short S[256][72];
    const int tid = threadIdx.x;
    const long px = (long)blockIdx.x * 256 + tid;
    const int bat = (int)(px >> 16);

    for (int i = tid; i < 288; i += 256) atts[i] = attb[bat * 288 + i];

    float v[48];
    #pragma unroll
    for (int i = 0; i < 6; i++) {
        b16x8 t = *(const b16x8*)&Qv[baddr(px, 18, 12 + i)];
        #pragma unroll
        for (int j = 0; j < 8; j++) v[i * 8 + j] = b2f((unsigned short)t[j]);
    }
    __syncthreads();

    #pragma unroll
    for (int h = 0; h < 8; h++) {
        unsigned short sh[6];
        #pragma unroll
        for (int c = 0; c < 6; c++) {
            float s = 0.f;
            #pragma unroll
            for (int d = 0; d < 6; d++) s = fmaf(atts[h * 36 + c * 6 + d], v[h * 6 + d], s);
            sh[c] = f2b(s);
        }
        #pragma unroll
        for (int i = 0; i < 3; i++) {
            unsigned packed = (unsigned)sh[2 * i] | ((unsigned)sh[2 * i + 1] << 16);
            *(unsigned*)&S[tid][h * 6 + 2 * i] = packed;
        }
    }
    #pragma unroll
    for (int i = 0; i < 8; i++) *(unsigned*)&S[tid][48 + 2 * i] = 0u;
    __syncthreads();

    const int lane = tid & 63, w = tid >> 6;
    const int lm = lane & 15, lk = lane >> 4;
    f32x4 acc[4][3];
    #pragma unroll
    for (int nt = 0; nt < 4; nt++)
        #pragma unroll
        for (int m = 0; m < 3; m++)
            #pragma unroll
            for (int j = 0; j < 4; j++) acc[nt][m][j] = 0.f;

    #pragma unroll
    for (int kc = 0; kc < 2; kc++) {
        b16x8 a[3];
        #pragma unroll
        for (int m = 0; m < 3; m++)
            a[m] = *(const b16x8*)&W16[(size_t)(m * 16 + lm) * 64 + kc * 32 + lk * 8];
        #pragma unroll
        for (int nt = 0; nt < 4; nt++) {
            b16x8 bb = *(const b16x8*)&S[w * 64 + nt * 16 + lm][kc * 32 + lk * 8];
            #pragma unroll
            for (int m = 0; m < 3; m++)
                acc[nt][m] = __builtin_amdgcn_mfma_f32_16x16x32_bf16(a[m], bb, acc[nt][m], 0, 0, 0);
        }
    }

    #pragma unroll
    for (int nt = 0; nt < 4; nt++) {
        const long px2 = (long)blockIdx.x * 256 + w * 64 + nt * 16 + lm;
        const int p2 = (int)(px2 & 65535);
        const long pxb2 = px2 >> 4;
        #pragma unroll
        for (int m = 0; m < 3; m++) {
            const int row = m * 16 + lk * 4;
            b16x4 o;
            #pragma unroll
            for (int j = 0; j < 4; j++) {
                float xv = x[((size_t)(bat * 48 + row + j) << 16) + p2];
                o[j] = (short)f2b(acc[nt][m][j] + xv);
            }
            const int ch = boff + row;
            *(b16x4*)&D16p[(pxb2 * 12 + (ch >> 3)) * 128 + lm * 8 + (ch & 7)] = o;
        }
    }
}

extern "C" void kernel_launch(void* const* d_in, const int* in_sizes, int n_in,
                              void* d_out, int out_size, void* d_ws, size_t ws_size,
                              hipStream_t stream) {
    const float* x1      = (const float*)d_in[0];
    const float* x2      = (const float*)d_in[1];
    const float* t1      = (const float*)d_in[2];
    const float* t2      = (const float*)d_in[3];
    const float* qkv1_w  = (const float*)d_in[4];
    const float* qkv1_dw = (const float*)d_in[5];
    const float* qkv2_w  = (const float*)d_in[6];
    const float* qkv2_dw = (const float*)d_in[7];
    const float* mid1_w  = (const float*)d_in[8];
    const float* mid2_w  = (const float*)d_in[9];
    const float* pE_w    = (const float*)d_in[10];
    const float* pE_dw   = (const float*)d_in[11];
    const float* pE1_w   = (const float*)d_in[12];
    const float* pE1_dw  = (const float*)d_in[13];
    const float* pE2_w   = (const float*)d_in[14];
    const float* pE2_dw  = (const float*)d_in[15];
    const float* po1_w   = (const float*)d_in[16];
    const float* po2_w   = (const float*)d_in[17];
    float* dout = (float*)d_out;
    char* ws = (char*)d_ws;

    // workspace layout (bytes); peak ~201.8 MB
    unsigned short* D16p  = (unsigned short*)(ws + 0);
    unsigned short* QKVc1 = (unsigned short*)(ws + 25165824);
    unsigned short* QKVc2 = (unsigned short*)(ws + 62914560);
    unsigned short* Q1    = (unsigned short*)(ws + 100663296);
    unsigned short* Q2    = (unsigned short*)(ws + 138412032);
    unsigned short* GH    = (unsigned short*)(ws + 25165824);     // phase5 overlay
    unsigned short* Xg    = (unsigned short*)(ws + 125829120);    // phase5 overlay
    float*          PART  = (float*)(ws + 176160768);
    float*          ATT   = (float*)(ws + 176357376);
    unsigned short* W16   = (unsigned short*)(ws + 176361984);
    float*          DWT   = (float*)(ws + 176632320);             // ends 176,670,336
    unsigned short* ACC   = (unsigned short*)(ws + 176670720);    // 25,165,824 B

    const dim3 blk(256);

    wprep_k<<<dim3(566), blk, 0, stream>>>(
        qkv1_w, qkv2_w, mid1_w, mid2_w, pE_w, pE1_w, pE2_w, po1_w, po2_w,
        qkv1_dw, qkv2_dw, pE_dw, pE1_dw, pE2_dw, W16, DWT);

    // phase 1: qkv conv (fp32 NCHW input), both branches in one launch
    gemm_k<144,2,2,1,0,0><<<dim3(1024,1,2), blk, 0, stream>>>(
        nullptr, x1, 48, W16, QKVc1, 18, 0, nullptr, nullptr, nullptr,
        x2, W16 + 9216, QKVc2);
    dw144_k<<<dim3(2304,1,2), blk, 0, stream>>>(QKVc1, Q1, QKVc2, Q2, DWT);

    // phase 2: fused norms+dots, softmax
    attnA_k<<<dim3(32,16,2), blk, 0, stream>>>(Q1, Q2, PART);
    attnB_k<<<dim3(32), dim3(64), 0, stream>>>(PART, t1, t2, ATT);

    // phase 3+4: attn-out + mid conv + residual -> D16p (both branches)
    mid_k<<<dim3(512,2), blk, 0, stream>>>(Q1, Q2, ATT, x1, x2, W16 + 18432, D16p);

    // phase 5: gated FFN tail per branch
    for (int br = 0; br < 2; br++) {
        gemm_k<96,3,2,0,0,2><<<dim3(4096), blk, 0, stream>>>(
            D16p, nullptr, 0, W16 + 24576 + br * 36864, GH, 48, 0,
            nullptr, nullptr, nullptr, nullptr, nullptr, nullptr);
        dwtail_k<<<dim3(6144), blk, 0, stream>>>(
            GH, Xg, DWT + 2592 + br * 192, DWT + (br ? 7776 : 6048));
        if (br == 0)
            gemm_k<96,6,2,0,0,0><<<dim3(1024,1), blk, 0, stream>>>(
                Xg, nullptr, 0, W16 + 98304, ACC, 12, 0, nullptr, nullptr, nullptr,
                nullptr, nullptr, nullptr);
        else
            gemm_k<96,6,2,0,3,0><<<dim3(1024,1), blk, 0, stream>>>(
                Xg, nullptr, 0, W16 + 116736, nullptr, 0, 0, dout, D16p, ACC,
                nullptr, nullptr, nullptr);
    }
}

// Round 20
// 354.094 us; speedup vs baseline: 1.1506x; 1.0675x over previous
//
#include <hip/hip_runtime.h>
#include <math.h>

#define HW_ 65536

typedef __attribute__((ext_vector_type(8))) short b16x8;
typedef __attribute__((ext_vector_type(4))) short b16x4;
typedef __attribute__((ext_vector_type(4))) float f32x4;
typedef __attribute__((ext_vector_type(2))) float f32x2;

__device__ __forceinline__ unsigned short f2b(float f) {
    union { float f; unsigned u; } v; v.f = f;
    unsigned r = v.u + 0x7fffu + ((v.u >> 16) & 1u);
    return (unsigned short)(r >> 16);
}
__device__ __forceinline__ float b2f(unsigned short h) {
    union { unsigned u; float f; } v; v.u = ((unsigned)h) << 16; return v.f;
}
__device__ __forceinline__ float gelu_f(float x) {
    float t = 0.7978845608f * fmaf(0.044715f * x, x * x, x);
    float e = __expf(2.f * t);
    float th = 1.f - 2.f / (e + 1.f);
    return 0.5f * x * (1.f + th);
}

// packed dual-fma: v_pk_fma_f32 on CDNA (falls back to scalar if unavailable)
__device__ __forceinline__ f32x2 pk_fma(f32x2 a, f32x2 b, f32x2 c) {
#if __has_builtin(__builtin_elementwise_fma)
    return __builtin_elementwise_fma(a, b, c);
#else
    f32x2 r; r[0] = fmaf(a[0], b[0], c[0]); r[1] = fmaf(a[1], b[1], c[1]);
    return r;
#endif
}

__device__ __forceinline__ float wave_reduce_sum(float v) {
    #pragma unroll
    for (int off = 32; off; off >>= 1) v += __shfl_down(v, off, 64);
    return v;
}

// Blocked bf16 layout: element (px, ch) of a CC*8-channel tensor lives at
//   ((px>>4)*CC + (ch>>3))*128 + (px&15)*8 + (ch&7)
__device__ __forceinline__ size_t baddr(long px, int CC, int g) {
    return (((size_t)(px >> 4)) * CC + g) * 128 + ((size_t)(px & 15) << 3);
}

// ---------------------------------------------------------------------------
// Weight prep. bf16: Wq1@0[144][64] Wq2@9216 Wm1@18432[48][64] Wm2@21504
//   WGH1@24576[384][96] WGH2@61440 Wo@98304[96][384] (cols 0-191=po1,
//   192-383=po2); end 135168.
// fp32 dwt unchanged.
// ---------------------------------------------------------------------------
__global__ __launch_bounds__(256) void wprep_k(
    const float* __restrict__ q1w, const float* __restrict__ q2w,
    const float* __restrict__ m1w, const float* __restrict__ m2w,
    const float* __restrict__ pEw, const float* __restrict__ p1w,
    const float* __restrict__ p2w, const float* __restrict__ o1w,
    const float* __restrict__ o2w,
    const float* __restrict__ q1dw, const float* __restrict__ q2dw,
    const float* __restrict__ pEdw, const float* __restrict__ p1dw,
    const float* __restrict__ p2dw,
    unsigned short* __restrict__ wt, float* __restrict__ dwt)
{
    const int idx = blockIdx.x * 256 + threadIdx.x;
    if (idx < 135168) {
        const int base[8] = {0,9216,18432,21504,24576,61440,98304,135168};
        int s = 0;
        #pragma unroll
        for (int i = 1; i < 8; i++) if (idx >= base[i]) s = i;
        const int local = idx - base[s];
        float v = 0.f;
        if (s < 4) {
            const int m = local >> 6, k = local & 63;
            const float* src = (s == 0) ? q1w : (s == 1) ? q2w : (s == 2) ? m1w : m2w;
            if (k < 48) v = src[m * 48 + k];
        } else if (s < 6) {
            const int br = s - 4;
            const int m = local / 96, k = local % 96;
            if (m < 192) {
                v = pEw[(size_t)(br * 192 + m) * 96 + k];
            } else {
                const float* p12 = br ? p2w : p1w;
                const int lo = br * 48, m2 = m - 192;
                if (k >= lo && k < lo + 48) v = p12[m2 * 48 + (k - lo)];
            }
        } else {
            const int m = local / 384, k = local % 384;
            v = (k < 192) ? o1w[m * 192 + k] : o2w[m * 192 + (k - 192)];
        }
        wt[idx] = f2b(v);
    } else if (idx < 135168 + 9504) {
        const int d = idx - 135168;
        const int dbase[5] = {0,1296,2592,6048,7776};
        const int Cs[5] = {144,144,384,192,192};
        int s = 0;
        #pragma unroll
        for (int i = 1; i < 5; i++) if (d >= dbase[i]) s = i;
        const int local = d - dbase[s], C = Cs[s];
        const int t = local / C, c = local % C;
        const float* src = (s == 0) ? q1dw : (s == 1) ? q2dw : (s == 2) ? pEdw
                         : (s == 3) ? p1dw : p2dw;
        dwt[d] = src[c * 9 + t];
    }
}

// ---------------------------------------------------------------------------
// MFMA GEMM. KSPLIT: kc < KC/2 reads B16, kc >= KC/2 reads acc16 (as second
// B tensor), each with CCB = (KC/2)*4 chunks (used for the K=384 po gemm).
// ---------------------------------------------------------------------------
template<int BM, int KC, int NT, int BSRC, int EPI, int GRIDMODE, bool KSPLIT = false>
__global__ __launch_bounds__(256) void gemm_k(
    const unsigned short* __restrict__ B16,
    const float* __restrict__ Bf32, int Cin,
    const unsigned short* __restrict__ W16,
    unsigned short* __restrict__ out16, int CCo, int Coff,
    float* __restrict__ outf, const unsigned short* __restrict__ res,
    const unsigned short* __restrict__ acc16,
    const float* __restrict__ Bf32b, const unsigned short* __restrict__ W16b,
    unsigned short* __restrict__ out16b)
{
    constexpr int MF = BM / 16;
    const int tid = threadIdx.x;
    const int lane = tid & 63, w = tid >> 6;
    const int lm = lane & 15, lk = lane >> 4;

    int mb, pxblk;
    if (GRIDMODE == 2) {
        const int bx = blockIdx.x;                  // 4096 blocks
        const int sb = (bx & 7) * 512 + (bx >> 3);  // XCD-contiguous
        mb = sb & 3; pxblk = sb >> 2;
    } else {
        mb = blockIdx.y; pxblk = blockIdx.x;
    }

    const float* Bf = Bf32;
    const unsigned short* Wp = W16;
    unsigned short* outp = out16;
    if (GRIDMODE == 0 && BSRC == 1 && blockIdx.z) {
        Bf = Bf32b; Wp = W16b; outp = out16b;
    }

    const int m0 = mb * BM;
    const long wavepx = ((long)pxblk * 4 + w) * (NT * 16);
    const long pxb0 = wavepx >> 4;

    f32x4 acc[NT][MF];
    #pragma unroll
    for (int nt = 0; nt < NT; nt++)
        #pragma unroll
        for (int m = 0; m < MF; m++)
            #pragma unroll
            for (int j = 0; j < 4; j++) acc[nt][m][j] = 0.f;

    #pragma unroll
    for (int kc = 0; kc < KC; kc++) {
        b16x8 a[MF];
        #pragma unroll
        for (int m = 0; m < MF; m++)
            a[m] = *(const b16x8*)&Wp[(size_t)(m0 + m * 16 + lm) * (KC * 32) + kc * 32 + lk * 8];
        #pragma unroll
        for (int nt = 0; nt < NT; nt++) {
            b16x8 bb;
            if (BSRC == 0) {
                if (KSPLIT) {
                    const unsigned short* Bs = (kc >= KC / 2) ? acc16 : B16;
                    const int kc2 = (kc >= KC / 2) ? kc - KC / 2 : kc;
                    bb = *(const b16x8*)&Bs[((pxb0 + nt) * ((KC / 2) * 4) + (kc2 * 4 + lk)) * 128 + lm * 8];
                } else {
                    bb = *(const b16x8*)&B16[((pxb0 + nt) * (KC * 4) + (kc * 4 + lk)) * 128 + lm * 8];
                }
            } else {
                const long px = wavepx + nt * 16 + lm;
                const int p = (int)(px & 65535), bat = (int)(px >> 16);
                #pragma unroll
                for (int j = 0; j < 8; j++) {
                    const int c = kc * 32 + lk * 8 + j;
                    float v = (c < Cin) ? Bf[((size_t)(bat * Cin + c) << 16) + p] : 0.f;
                    bb[j] = (short)f2b(v);
                }
            }
            #pragma unroll
            for (int m = 0; m < MF; m++)
                acc[nt][m] = __builtin_amdgcn_mfma_f32_16x16x32_bf16(a[m], bb, acc[nt][m], 0, 0, 0);
        }
    }

    #pragma unroll
    for (int nt = 0; nt < NT; nt++) {
        const long px = wavepx + nt * 16 + lm;
        #pragma unroll
        for (int m = 0; m < MF; m++) {
            const int mrow = m * 16 + lk * 4;
            if (EPI == 0) {
                b16x4 o;
                #pragma unroll
                for (int j = 0; j < 4; j++) o[j] = (short)f2b(acc[nt][m][j]);
                const int ch = Coff + m0 + mrow;
                *(b16x4*)&outp[((pxb0 + nt) * CCo + (ch >> 3)) * 128 + lm * 8 + (ch & 7)] = o;
            } else if (EPI == 1) {
                const int p = (int)(px & 65535), bat = (int)(px >> 16);
                b16x4 r4 = *(const b16x4*)&res[((pxb0 + nt) * 12 + (mrow >> 3)) * 128 + lm * 8 + (mrow & 7)];
                #pragma unroll
                for (int j = 0; j < 4; j++)
                    outf[((size_t)(bat * 96 + mrow + j) << 16) + p]
                        = acc[nt][m][j] + b2f((unsigned short)r4[j]);
            } else if (EPI == 2) {
                const int p = (int)(px & 65535), bat = (int)(px >> 16);
                #pragma unroll
                for (int j = 0; j < 4; j++) {
                    const size_t adr = ((size_t)(bat * 96 + mrow + j) << 16) + p;
                    outf[adr] += acc[nt][m][j];
                }
            }
        }
    }
}

// ---------------------------------------------------------------------------
// Packed unpack: uint4 (8 bf16) -> 4 x f32x2.
// ---------------------------------------------------------------------------
__device__ __forceinline__ void unpack8v(const uint4 u, f32x2 f[4]) {
    union { unsigned u; float f; } a, b;
    a.u = u.x << 16; b.u = u.x & 0xFFFF0000u; f[0][0] = a.f; f[0][1] = b.f;
    a.u = u.y << 16; b.u = u.y & 0xFFFF0000u; f[1][0] = a.f; f[1][1] = b.f;
    a.u = u.z << 16; b.u = u.z & 0xFFFF0000u; f[2][0] = a.f; f[2][1] = b.f;
    a.u = u.w << 16; b.u = u.w & 0xFFFF0000u; f[3][0] = a.f; f[3][1] = b.f;
}

// ---------------------------------------------------------------------------
// dw 2px row core: 4 cols (1 left halo, 2 center, 1 right halo).
// ---------------------------------------------------------------------------
__device__ __forceinline__ void dw_row2(
    f32x2 acc[2][4], const unsigned short* __restrict__ T,
    size_t cb, long lOff, long rOff, bool lval, bool rval,
    const float* __restrict__ wrow, int wstr)
{
    f32x2 w[3][4];
    #pragma unroll
    for (int tx = 0; tx < 3; tx++) {
        const float4 a = *(const float4*)(wrow + (size_t)tx * wstr);
        const float4 b = *(const float4*)(wrow + (size_t)tx * wstr + 4);
        w[tx][0][0] = a.x; w[tx][0][1] = a.y;
        w[tx][1][0] = a.z; w[tx][1][1] = a.w;
        w[tx][2][0] = b.x; w[tx][2][1] = b.y;
        w[tx][3][0] = b.z; w[tx][3][1] = b.w;
    }
    uint4 u[4];
    if (lval) u[0] = *(const uint4*)&T[cb + lOff];
    else      u[0] = make_uint4(0u, 0u, 0u, 0u);
    u[1] = *(const uint4*)&T[cb];
    u[2] = *(const uint4*)&T[cb + 8];
    if (rval) u[3] = *(const uint4*)&T[cb + rOff];
    else      u[3] = make_uint4(0u, 0u, 0u, 0u);

    #pragma unroll
    for (int c = 0; c < 4; c++) {        // input col = px0 - 1 + c
        f32x2 f[4];
        unpack8v(u[c], f);
        #pragma unroll
        for (int tx = 0; tx < 3; tx++) {
            const int p = c - tx;        // output px using this col at tap tx
            if (p >= 0 && p < 2)
                #pragma unroll
                for (int q = 0; q < 4; q++)
                    acc[p][q] = pk_fma(w[tx][q], f[q], acc[p][q]);
        }
    }
}

// phase-1 depthwise: 144 ch (18 chunks), 2px x 8ch per thread, both branches
// via blockIdx.z. 4608 blocks, XCD y-banded.
__global__ __launch_bounds__(256) void dw144_k(
    const unsigned short* __restrict__ in1, unsigned short* __restrict__ out1,
    const unsigned short* __restrict__ in2, unsigned short* __restrict__ out2,
    const float* __restrict__ dwt)
{
    const int z = blockIdx.z;
    const unsigned short* in = z ? in2 : in1;
    unsigned short* out = z ? out2 : out1;
    const float* wt = dwt + z * 1296;
    const int bx = blockIdx.x;
    const int sb = (bx & 7) * 576 + (bx >> 3);
    const int idx = sb * 256 + threadIdx.x;   // < 1,179,648
    const int pbi = idx / 144;
    const int rem = idx - pbi * 144;
    const int g = rem >> 3, i = rem & 7;
    const long px0 = (long)pbi * 16 + i * 2;
    const int x0 = (int)(px0 & 255);
    const int y = (int)((px0 >> 8) & 255);
    const bool lval = x0 > 0, rval = x0 < 254;
    const int off = (int)(px0 & 15) * 8;
    const size_t cb0 = ((size_t)(px0 >> 4) * 18 + g) * 128 + off;
    const long lOff = (off == 0) ? (120 - 18 * 128) : -8;
    const long rOff = (off == 112) ? (18 * 128 - 112) : 16;
    const long dyStep = 16 * 18 * 128;

    f32x2 acc[2][4];
    #pragma unroll
    for (int p = 0; p < 2; p++)
        #pragma unroll
        for (int q = 0; q < 4; q++) { acc[p][q][0] = 0.f; acc[p][q][1] = 0.f; }

    #pragma unroll
    for (int dy = -1; dy <= 1; dy++) {
        const int yy = y + dy;
        if ((unsigned)yy >= 256u) continue;
        const size_t cb = cb0 + (size_t)((long)dy * dyStep);
        dw_row2(acc, in, cb, lOff, rOff, lval, rval,
                wt + g * 8 + (size_t)(dy + 1) * 3 * 144, 144);
    }

    #pragma unroll
    for (int p = 0; p < 2; p++) {
        b16x8 o;
        #pragma unroll
        for (int j = 0; j < 8; j++) o[j] = (short)f2b(acc[p][j >> 1][j & 1]);
        *(b16x8*)&out[cb0 + (size_t)p * 8] = o;
    }
}

// tail fused: Xg = gelu(dw(GH ch 0..191)) * dw(GH ch 192..383). blocked.
// 2px x 8ch per thread, 6144 blocks, XCD y-banded (r19 proven, 57 us).
__global__ __launch_bounds__(256) void dwtail_k(
    const unsigned short* __restrict__ GH, unsigned short* __restrict__ Xg,
    const float* __restrict__ dwtG, const float* __restrict__ dwtH)
{
    const int bx = blockIdx.x;
    const int sb = (bx & 7) * 768 + (bx >> 3);
    const int idx = sb * 256 + threadIdx.x;   // < 1572864
    const int pbi = idx / 192;
    const int rem = idx - pbi * 192;
    const int g = rem >> 3, i = rem & 7;
    const long px0 = (long)pbi * 16 + i * 2;
    const int x0 = (int)(px0 & 255);
    const int y = (int)((px0 >> 8) & 255);
    const bool lval = x0 > 0, rval = x0 < 254;
    const int off = (int)(px0 & 15) * 8;
    const size_t cb0 = ((size_t)(px0 >> 4) * 48 + g) * 128 + off;   // G base
    const long lOff = (off == 0) ? (120 - 48 * 128) : -8;
    const long rOff = (off == 112) ? (48 * 128 - 112) : 16;
    const long dyStep = 16 * 48 * 128;

    f32x2 aG[2][4], aH[2][4];
    #pragma unroll
    for (int p = 0; p < 2; p++)
        #pragma unroll
        for (int q = 0; q < 4; q++) {
            aG[p][q][0] = 0.f; aG[p][q][1] = 0.f;
            aH[p][q][0] = 0.f; aH[p][q][1] = 0.f;
        }

    #pragma unroll
    for (int dy = -1; dy <= 1; dy++) {
        const int yy = y + dy;
        if ((unsigned)yy >= 256u) continue;
        const size_t cb = cb0 + (size_t)((long)dy * dyStep);
        dw_row2(aG, GH, cb, lOff, rOff, lval, rval,
                dwtG + g * 8 + (size_t)(dy + 1) * 3 * 384, 384);
        dw_row2(aH, GH, cb + 3072, lOff, rOff, lval, rval,
                dwtH + g * 8 + (size_t)(dy + 1) * 3 * 192, 192);
    }

    const size_t ob = ((size_t)(px0 >> 4) * 24 + g) * 128 + off;
    #pragma unroll
    for (int p = 0; p < 2; p++) {
        b16x8 o;
        #pragma unroll
        for (int j = 0; j < 8; j++)
            o[j] = (short)f2b(gelu_f(aG[p][j >> 1][j & 1]) * aH[p][j >> 1][j & 1]);
        *(b16x8*)&Xg[ob + (size_t)p * 8] = o;
    }
}

// ---------------------------------------------------------------------------
// Attention stage A (unchanged).
// ---------------------------------------------------------------------------
__global__ __launch_bounds__(256) void attnA_k(
    const unsigned short* __restrict__ Q1, const unsigned short* __restrict__ Q2,
    float* __restrict__ part)
{
    const int tid = threadIdx.x;
    const int chunk = blockIdx.x, bh = blockIdx.y, a = blockIdx.z;
    const int b = bh >> 3, h = bh & 7;
    const unsigned* Qq = (const unsigned*)(a ? Q1 : Q2);
    const unsigned* Qk = (const unsigned*)(a ? Q2 : Q1);
    const int u0 = h * 3;
    const int cq = u0 >> 2, o = u0 & 3;
    const int ck = (24 + u0) >> 2;

    float dot[36], nq[6], nk[6];
    #pragma unroll
    for (int i = 0; i < 36; i++) dot[i] = 0.f;
    #pragma unroll
    for (int i = 0; i < 6; i++) { nq[i] = 0.f; nk[i] = 0.f; }

    #pragma unroll 1
    for (int r = 0; r < 8; r++) {
        const long px = (long)b * 65536 + chunk * 2048 + r * 256 + tid;
        const size_t rowu = ((size_t)(px >> 4)) * 18 * 64 + ((px & 15) << 2);
        const uint4 qa = *(const uint4*)&Qq[rowu + (size_t)cq * 64];
        const uint4 qb = *(const uint4*)&Qq[rowu + (size_t)(cq + 1) * 64];
        const uint4 ka = *(const uint4*)&Qk[rowu + (size_t)ck * 64];
        const uint4 kb = *(const uint4*)&Qk[rowu + (size_t)(ck + 1) * 64];
        unsigned uq[3], uk[3];
        if (o == 0)      { uq[0]=qa.x; uq[1]=qa.y; uq[2]=qa.z; uk[0]=ka.x; uk[1]=ka.y; uk[2]=ka.z; }
        else if (o == 1) { uq[0]=qa.y; uq[1]=qa.z; uq[2]=qa.w; uk[0]=ka.y; uk[1]=ka.z; uk[2]=ka.w; }
        else if (o == 2) { uq[0]=qa.z; uq[1]=qa.w; uq[2]=qb.x; uk[0]=ka.z; uk[1]=ka.w; uk[2]=kb.x; }
        else             { uq[0]=qa.w; uq[1]=qb.x; uq[2]=qb.y; uk[0]=ka.w; uk[1]=kb.x; uk[2]=kb.y; }
        float q[6], k[6];
        #pragma unroll
        for (int i = 0; i < 3; i++) {
            union { unsigned u; float f; } lo, hi;
            lo.u = uq[i] << 16; hi.u = uq[i] & 0xFFFF0000u;
            q[2 * i] = lo.f; q[2 * i + 1] = hi.f;
            lo.u = uk[i] << 16; hi.u = uk[i] & 0xFFFF0000u;
            k[2 * i] = lo.f; k[2 * i + 1] = hi.f;
        }
        #pragma unroll
        for (int c = 0; c < 6; c++) nq[c] = fmaf(q[c], q[c], nq[c]);
        #pragma unroll
        for (int d = 0; d < 6; d++) nk[d] = fmaf(k[d], k[d], nk[d]);
        #pragma unroll
        for (int c = 0; c < 6; c++)
            #pragma unroll
            for (int d = 0; d < 6; d++) dot[c * 6 + d] = fmaf(q[c], k[d], dot[c * 6 + d]);
    }

    __shared__ float red[4][48];
    const int lane = tid & 63, wid = tid >> 6;
    #pragma unroll
    for (int i = 0; i < 48; i++) {
        float v = (i < 36) ? dot[i] : (i < 42 ? nq[i - 36] : nk[i - 42]);
        v = wave_reduce_sum(v);
        if (!lane) red[wid][i] = v;
    }
    __syncthreads();
    if (tid < 48)
        part[((size_t)((a * 16 + bh) * 32 + chunk)) * 48 + tid]
            = red[0][tid] + red[1][tid] + red[2][tid] + red[3][tid];
}

__global__ void attnB_k(const float* __restrict__ part,
                        const float* __restrict__ t1, const float* __restrict__ t2,
                        float* __restrict__ att)
{
    const int abh = blockIdx.x, tid = threadIdx.x;
    const int a = abh >> 4, b = (abh >> 3) & 1, h = abh & 7;
    __shared__ float s[48];
    if (tid < 48) {
        float v = 0.f;
        for (int ch = 0; ch < 32; ch++) v += part[((size_t)abh * 32 + ch) * 48 + tid];
        s[tid] = v;
    }
    __syncthreads();
    if (tid < 6) {
        const int c = tid;
        const float tv = a ? t2[h] : t1[h];
        const float qn = fmaxf(sqrtf(s[36 + c]), 1e-12f);
        float raw[6];
        #pragma unroll
        for (int d = 0; d < 6; d++)
            raw[d] = tv * s[c * 6 + d] / (qn * fmaxf(sqrtf(s[42 + d]), 1e-12f));
        float m = raw[0];
        #pragma unroll
        for (int d = 1; d < 6; d++) m = fmaxf(m, raw[d]);
        float e[6], sum = 0.f;
        #pragma unroll
        for (int d = 0; d < 6; d++) { e[d] = expf(raw[d] - m); sum += e[d]; }
        const float inv = 1.f / sum;
        #pragma unroll
        for (int d = 0; d < 6; d++)
            att[((size_t)(a * 2 + b) * 8 + h) * 36 + c * 6 + d] = e[d] * inv;
    }
}

// ---------------------------------------------------------------------------
// Fused attn-out + mid conv + residual (unchanged).
// ---------------------------------------------------------------------------
__global__ __launch_bounds__(256) void mid_k(
    const unsigned short* __restrict__ Q1, const unsigned short* __restrict__ Q2,
    const float* __restrict__ att,
    const float* __restrict__ x1, const float* __restrict__ x2,
    const unsigned short* __restrict__ Wm, unsigned short* __restrict__ D16p)
{
    const int br = blockIdx.y;
    const unsigned short* Qv = br ? Q2 : Q1;
    const float* x = br ? x2 : x1;
    const unsigned short* W16 = Wm + br * 3072;
    const float* attb = att + br * 576;
    const int boff = br * 48;

    __shared__ float atts[288];
    __shared__ unsigned short S[256][72];
    const int tid = threadIdx.x;
    const long px = (long)blockIdx.x * 256 + tid;
    const int bat = (int)(px >> 16);

    for (int i = tid; i < 288; i += 256) atts[i] = attb[bat * 288 + i];

    float v[48];
    #pragma unroll
    for (int i = 0; i < 6; i++) {
        b16x8 t = *(const b16x8*)&Qv[baddr(px, 18, 12 + i)];
        #pragma unroll
        for (int j = 0; j < 8; j++) v[i * 8 + j] = b2f((unsigned short)t[j]);
    }
    __syncthreads();

    #pragma unroll
    for (int h = 0; h < 8; h++) {
        unsigned short sh[6];
        #pragma unroll
        for (int c = 0; c < 6; c++) {
            float s = 0.f;
            #pragma unroll
            for (int d = 0; d < 6; d++) s = fmaf(atts[h * 36 + c * 6 + d], v[h * 6 + d], s);
            sh[c] = f2b(s);
        }
        #pragma unroll
        for (int i = 0; i < 3; i++) {
            unsigned packed = (unsigned)sh[2 * i] | ((unsigned)sh[2 * i + 1] << 16);
            *(unsigned*)&S[tid][h * 6 + 2 * i] = packed;
        }
    }
    #pragma unroll
    for (int i = 0; i < 8; i++) *(unsigned*)&S[tid][48 + 2 * i] = 0u;
    __syncthreads();

    const int lane = tid & 63, w = tid >> 6;
    const int lm = lane & 15, lk = lane >> 4;
    f32x4 acc[4][3];
    #pragma unroll
    for (int nt = 0; nt < 4; nt++)
        #pragma unroll
        for (int m = 0; m < 3; m++)
            #pragma unroll
            for (int j = 0; j < 4; j++) acc[nt][m][j] = 0.f;

    #pragma unroll
    for (int kc = 0; kc < 2; kc++) {
        b16x8 a[3];
        #pragma unroll
        for (int m = 0; m < 3; m++)
            a[m] = *(const b16x8*)&W16[(size_t)(m * 16 + lm) * 64 + kc * 32 + lk * 8];
        #pragma unroll
        for (int nt = 0; nt < 4; nt++) {
            b16x8 bb = *(const b16x8*)&S[w * 64 + nt * 16 + lm][kc * 32 + lk * 8];
            #pragma unroll
            for (int m = 0; m < 3; m++)
                acc[nt][m] = __builtin_amdgcn_mfma_f32_16x16x32_bf16(a[m], bb, acc[nt][m], 0, 0, 0);
        }
    }

    #pragma unroll
    for (int nt = 0; nt < 4; nt++) {
        const long px2 = (long)blockIdx.x * 256 + w * 64 + nt * 16 + lm;
        const int p2 = (int)(px2 & 65535);
        const long pxb2 = px2 >> 4;
        #pragma unroll
        for (int m = 0; m < 3; m++) {
            const int row = m * 16 + lk * 4;
            b16x4 o;
            #pragma unroll
            for (int j = 0; j < 4; j++) {
                float xv = x[((size_t)(bat * 48 + row + j) << 16) + p2];
                o[j] = (short)f2b(acc[nt][m][j] + xv);
            }
            const int ch = boff + row;
            *(b16x4*)&D16p[(pxb2 * 12 + (ch >> 3)) * 128 + lm * 8 + (ch & 7)] = o;
        }
    }
}

extern "C" void kernel_launch(void* const* d_in, const int* in_sizes, int n_in,
                              void* d_out, int out_size, void* d_ws, size_t ws_size,
                              hipStream_t stream) {
    const float* x1      = (const float*)d_in[0];
    const float* x2      = (const float*)d_in[1];
    const float* t1      = (const float*)d_in[2];
    const float* t2      = (const float*)d_in[3];
    const float* qkv1_w  = (const float*)d_in[4];
    const float* qkv1_dw = (const float*)d_in[5];
    const float* qkv2_w  = (const float*)d_in[6];
    const float* qkv2_dw = (const float*)d_in[7];
    const float* mid1_w  = (const float*)d_in[8];
    const float* mid2_w  = (const float*)d_in[9];
    const float* pE_w    = (const float*)d_in[10];
    const float* pE_dw   = (const float*)d_in[11];
    const float* pE1_w   = (const float*)d_in[12];
    const float* pE1_dw  = (const float*)d_in[13];
    const float* pE2_w   = (const float*)d_in[14];
    const float* pE2_dw  = (const float*)d_in[15];
    const float* po1_w   = (const float*)d_in[16];
    const float* po2_w   = (const float*)d_in[17];
    float* dout = (float*)d_out;
    char* ws = (char*)d_ws;

    // workspace layout (bytes); peak 227.00 MB (round-2 run proved >=227.14)
    unsigned short* D16p  = (unsigned short*)(ws + 0);             // 12 chunks
    unsigned short* QKVc1 = (unsigned short*)(ws + 25165824);      // phases 1-4
    unsigned short* QKVc2 = (unsigned short*)(ws + 62914560);
    unsigned short* Q1    = (unsigned short*)(ws + 100663296);
    unsigned short* Q2    = (unsigned short*)(ws + 138412032);     // ends 176160768
    unsigned short* GH    = (unsigned short*)(ws + 25165824);      // phase5 overlay
    unsigned short* Xg1   = (unsigned short*)(ws + 125829120);     // 50,331,648 B
    unsigned short* Xg2   = (unsigned short*)(ws + 176160768);     // 50,331,648 B
    unsigned short* W16   = (unsigned short*)(ws + 226492416);     // 270,336 B
    float*          DWT   = (float*)(ws + 226762752);              // 38,016 B
    float*          PART  = (float*)(ws + 226800768);              // 196,608 B
    float*          ATT   = (float*)(ws + 226997376);              // 4,608 B

    const dim3 blk(256);

    wprep_k<<<dim3(566), blk, 0, stream>>>(
        qkv1_w, qkv2_w, mid1_w, mid2_w, pE_w, pE1_w, pE2_w, po1_w, po2_w,
        qkv1_dw, qkv2_dw, pE_dw, pE1_dw, pE2_dw, W16, DWT);

    // phase 1: qkv conv (fp32 NCHW input), both branches in one launch
    gemm_k<144,2,2,1,0,0><<<dim3(1024,1,2), blk, 0, stream>>>(
        nullptr, x1, 48, W16, QKVc1, 18, 0, nullptr, nullptr, nullptr,
        x2, W16 + 9216, QKVc2);
    dw144_k<<<dim3(4608,1,2), blk, 0, stream>>>(QKVc1, Q1, QKVc2, Q2, DWT);

    // phase 2: fused norms+dots, softmax
    attnA_k<<<dim3(32,16,2), blk, 0, stream>>>(Q1, Q2, PART);
    attnB_k<<<dim3(32), dim3(64), 0, stream>>>(PART, t1, t2, ATT);

    // phase 3+4: attn-out + mid conv + residual -> D16p (both branches)
    mid_k<<<dim3(512,2), blk, 0, stream>>>(Q1, Q2, ATT, x1, x2, W16 + 18432, D16p);

    // phase 5: per branch GH gemm + fused dw/gelu -> Xg{1,2}
    for (int br = 0; br < 2; br++) {
        gemm_k<96,3,2,0,0,2><<<dim3(4096), blk, 0, stream>>>(
            D16p, nullptr, 0, W16 + 24576 + br * 36864, GH, 48, 0,
            nullptr, nullptr, nullptr, nullptr, nullptr, nullptr);
        dwtail_k<<<dim3(6144), blk, 0, stream>>>(
            GH, br ? Xg2 : Xg1, DWT + 2592 + br * 192, DWT + (br ? 7776 : 6048));
    }

    // final: dout = D16p + [po1|po2] @ [Xg1;Xg2]  (K=384, single fp32 write)
    gemm_k<96,12,2,0,1,0,true><<<dim3(1024,1), blk, 0, stream>>>(
        Xg1, nullptr, 0, W16 + 98304, nullptr, 0, 0, dout, D16p, Xg2,
        nullptr, nullptr, nullptr);
}